// Round 2
// 558.753 us; speedup vs baseline: 1.0162x; 1.0162x over previous
//
#include <hip/hip_runtime.h>

#define HW40 1600
typedef unsigned short ushort_t;
typedef __attribute__((ext_vector_type(8))) short short8;
typedef __attribute__((ext_vector_type(4))) short short4v;
typedef __attribute__((ext_vector_type(4))) float f4v;

__device__ __forceinline__ float bu(ushort_t u) {
  union { unsigned i; float f; } x; x.i = ((unsigned)u) << 16; return x.f;
}
__device__ __forceinline__ ushort_t fb(float f) {
  union { float f; unsigned i; } x; x.f = f;
  unsigned r = x.i + 0x7FFFu + ((x.i >> 16) & 1u);
  return (ushort_t)(r >> 16);
}

#define GLD16(g, l)                                                            \
  __builtin_amdgcn_global_load_lds(                                            \
      (const __attribute__((address_space(1))) void*)(g),                      \
      (__attribute__((address_space(3))) void*)(l), 16, 0, 0)

#define PART_STRIDE 1638400  // one split-K slice: 256 x 6400

// ---------------------------------------------------------------------------
// Merged prep: zero page + 3x convert_w9 + convert_dcnw in ONE launch.
// g <  576 : com_w0 -> Acom0 (48 pad 64)
// g < 1152 : com_w1 -> Acom1 (48 pad 64)
// g < 3456 : res_w  -> Ares  (256)
// g < 3968 : dcn weights -> A0/A1
// g = 3968 : zero page
// ---------------------------------------------------------------------------
__global__ __launch_bounds__(256) void prep_all(
    const float* __restrict__ com_w0, const float* __restrict__ com_w1,
    const float* __restrict__ res_w, const float* __restrict__ dcn_w0,
    const float* __restrict__ dcn_w1, ushort_t* __restrict__ Acom0,
    ushort_t* __restrict__ Acom1, ushort_t* __restrict__ Ares,
    ushort_t* __restrict__ A0, ushort_t* __restrict__ A1,
    ushort_t* __restrict__ zp) {
  __shared__ float s[4096];
  const int g = blockIdx.x;
  const int t = threadIdx.x;
  if (g < 3456) {
    // 3x3 conv weights [co][cin][3][3] fp32 -> A[co][tap*256+cin] bf16
    const float* src; ushort_t* dst; int Cout_src; int base;
    if (g < 576)       { src = com_w0; dst = Acom0; Cout_src = 48;  base = g; }
    else if (g < 1152) { src = com_w1; dst = Acom1; Cout_src = 48;  base = g - 576; }
    else               { src = res_w;  dst = Ares;  Cout_src = 256; base = g - 1152; }
    const int idx = base * 256 + t;
    const int co = idx / 2304;
    const int k  = idx - co * 2304;
    const int cin = k & 255, tap = k >> 8;
    dst[idx] = (co < Cout_src) ? fb(src[(size_t)co * 2304 + cin * 9 + tap]) : (ushort_t)0;
  } else if (g < 3968) {
    // dcn weights [co][cin][16] fp32 -> A_bf16 [co][k = i*256 + cin]
    const int lg = g - 3456;
    const int co = lg & 255;
    const float* w = (lg < 256) ? dcn_w0 : dcn_w1;
    ushort_t* A = (lg < 256) ? A0 : A1;
    const float4* wp = (const float4*)(w + (size_t)co * 4096);
#pragma unroll
    for (int q = 0; q < 4; ++q) ((float4*)s)[t + q * 256] = wp[t + q * 256];
    __syncthreads();
    const int i = t >> 4, cb = (t & 15) * 16;
    ushort_t tmp[16];
#pragma unroll
    for (int j = 0; j < 16; ++j) tmp[j] = fb(s[(cb + j) * 16 + i]);
    ushort_t* op = A + (size_t)co * 4096 + t * 16;
    ((uint4*)op)[0] = ((uint4*)tmp)[0];
    ((uint4*)op)[1] = ((uint4*)tmp)[1];
  } else {
    zp[t] = 0;  // zero page for OOB conv taps
  }
}

// ---------------------------------------------------------------------------
// Merged NCHW fp32 -> NHWC bf16 for f2 (->ft40), f1 (->f1t), f0 (->f0t).
// grid x: [0,50) f2 | [50,250) f1 | [250,1050) f0; y = c-tile, z = batch.
// ---------------------------------------------------------------------------
__global__ __launch_bounds__(256) void nhwc_all(const float* __restrict__ f2,
                                                const float* __restrict__ f1,
                                                const float* __restrict__ f0,
                                                ushort_t* __restrict__ ft40,
                                                ushort_t* __restrict__ f1t,
                                                ushort_t* __restrict__ f0t) {
  __shared__ float tile[32][33];
  const int gx = blockIdx.x;
  const float* x; ushort_t* xt; int HW, sblk;
  if (gx < 50)       { x = f2; xt = ft40; HW = 1600;  sblk = gx; }
  else if (gx < 250) { x = f1; xt = f1t;  HW = 6400;  sblk = gx - 50; }
  else               { x = f0; xt = f0t;  HW = 25600; sblk = gx - 250; }
  const int s0 = sblk * 32, c0 = blockIdx.y * 32, b = blockIdx.z;
  const int tx = threadIdx.x & 31, ty = threadIdx.x >> 5;
  const float* xb = x + ((size_t)b * 256 + c0) * HW + s0;
#pragma unroll
  for (int q = 0; q < 4; ++q) tile[ty + q * 8][tx] = xb[(size_t)(ty + q * 8) * HW + tx];
  __syncthreads();
  ushort_t* ob = xt + ((size_t)b * HW + s0) * 256 + c0;
#pragma unroll
  for (int q = 0; q < 4; ++q) {
    int srow = ty + q * 8;
    ob[(size_t)srow * 256 + tx] = fb(tile[tx][srow]);
  }
}

// ---------------------------------------------------------------------------
// Sampler (fused com-epilogue). XCD-contiguous work swizzle: 1D grid 800,
// work = (g&7)*100 + (g>>3). 8-px tiles, block 256. Sums 8 split-K slices
// (com conv now split-K 8 for CU fill).
// ---------------------------------------------------------------------------
__global__ __launch_bounds__(256) void sample_kernel(
    const ushort_t* __restrict__ xt, const ushort_t* __restrict__ part,
    const float* __restrict__ cbias, ushort_t* __restrict__ colT,
    int Hin, int Win, int stride, int pad, int dil) {
  __shared__ int4  gL[128];
  __shared__ float4 gW[128];
  const int g = blockIdx.x;
  const int work = (g & 7) * 100 + (g >> 3);
  const int b = work / 200;
  const int px0 = (work - b * 200) * 8;
  const int t = threadIdx.x;
  const int HWin = Hin * Win;

  if (t < 128) {  // geometry: pair pid = t -> (px_l = t&7, tap i = t>>3)
    const int px_l = t & 7, i = t >> 3;
    const int p = px0 + px_l;
    const int n = b * 1600 + p;
    const int ph = p / 40, pw = p - (p / 40) * 40;
    float dy = cbias[2 * i], dx = cbias[2 * i + 1], mzr = cbias[32 + i];
#pragma unroll
    for (int kz = 0; kz < 8; ++kz) {
      const ushort_t* pp = part + (size_t)kz * PART_STRIDE + n;
      dy  += bu(pp[(size_t)(2 * i) * 6400]);
      dx  += bu(pp[(size_t)(2 * i + 1) * 6400]);
      mzr += bu(pp[(size_t)(32 + i) * 6400]);
    }
    float mz = 1.f / (1.f + expf(-mzr));
    float py = (float)(ph * stride - pad + (i >> 2) * dil) + dy;
    float px = (float)(pw * stride - pad + (i & 3) * dil) + dx;
    float y0f = floorf(py), x0f = floorf(px);
    float ly = py - y0f, lx = px - x0f;
    int y0 = (int)y0f, x0 = (int)x0f;
    int y1 = y0 + 1, x1 = x0 + 1;
    float hy = 1.f - ly, hx = 1.f - lx;
    float w00 = hy * hx * mz, w01 = hy * lx * mz;
    float w10 = ly * hx * mz, w11 = ly * lx * mz;
    if (y0 < 0 || y0 >= Hin) { w00 = 0.f; w01 = 0.f; }
    if (y1 < 0 || y1 >= Hin) { w10 = 0.f; w11 = 0.f; }
    if (x0 < 0 || x0 >= Win) { w00 = 0.f; w10 = 0.f; }
    if (x1 < 0 || x1 >= Win) { w01 = 0.f; w11 = 0.f; }
    int cy0 = min(max(y0, 0), Hin - 1), cy1 = min(max(y1, 0), Hin - 1);
    int cx0 = min(max(x0, 0), Win - 1), cx1 = min(max(x1, 0), Win - 1);
    gL[t] = make_int4((cy0 * Win + cx0) * 256, (cy0 * Win + cx1) * 256,
                      (cy1 * Win + cx0) * 256, (cy1 * Win + cx1) * 256);
    gW[t] = make_float4(w00, w01, w10, w11);
  }
  __syncthreads();

  const ushort_t* xtb = xt + (size_t)b * HWin * 256;
  const int wv = t >> 6, l = t & 63;
  const int half = l >> 5;
  const int cin8 = (l & 31) * 8;

#pragma unroll 2
  for (int it = 0; it < 16; ++it) {
    const int pr = it * 8 + wv * 2 + half;
    const int4 G = gL[pr];
    const float4 W = gW[pr];
    short8 c00 = *(const short8*)(xtb + G.x + cin8);
    short8 c01 = *(const short8*)(xtb + G.y + cin8);
    short8 c10 = *(const short8*)(xtb + G.z + cin8);
    short8 c11 = *(const short8*)(xtb + G.w + cin8);
    short8 rr;
#pragma unroll
    for (int j = 0; j < 8; ++j) {
      float v = W.x * bu((ushort_t)c00[j]) + W.y * bu((ushort_t)c01[j]) +
                W.z * bu((ushort_t)c10[j]) + W.w * bu((ushort_t)c11[j]);
      rr[j] = (short)fb(v);
    }
    const int px_l = pr & 7, i = pr >> 3;
    *(short8*)(colT + ((size_t)(b * 1600 + px0 + px_l) * 4096 + i * 256 + cin8)) = rr;
  }
}

// ---------------------------------------------------------------------------
// Deform GEMM (K=4096, colT B-matrix), split-K 8, bf16 partials.
// ---------------------------------------------------------------------------
__global__ __launch_bounds__(256) void gemm_deform(const ushort_t* __restrict__ A,
                                                   const ushort_t* __restrict__ B,
                                                   ushort_t* __restrict__ part) {
  __shared__ ushort_t sA[128 * 32];
  __shared__ ushort_t sB[128 * 32];
  const int g = blockIdx.x;
  const int kz = g & 7, mt = (g >> 3) & 1, nt = g >> 4;
  const int t = threadIdx.x;
  const int wv = t >> 6, l = t & 63;
  const int wm = wv >> 1, wn = wv & 1;

  f4v acc[4][4];
#pragma unroll
  for (int a = 0; a < 4; ++a)
#pragma unroll
    for (int bb = 0; bb < 4; ++bb) acc[a][bb] = (f4v)(0.f);

  const int ra = t >> 2;
  const int q  = ((t & 3) - (ra >> 1)) & 3;
  const size_t aoff = (size_t)(mt * 128 + ra) * 4096 + q * 8;
  const size_t boff = (size_t)(nt * 128 + ra) * 4096 + q * 8;
  ushort_t* lA = sA + t * 8;
  ushort_t* lB = sB + t * 8;

  int k0 = kz * 512;
  const int lm = l & 15;
  const int koff = (((l >> 4) + (lm >> 1)) & 3) * 8;

  for (int step = 0; step < 16; ++step, k0 += 32) {
    __syncthreads();
    GLD16(A + aoff + k0, lA);
    GLD16(A + aoff + (size_t)64 * 4096 + k0, lA + 2048);
    GLD16(B + boff + k0, lB);
    GLD16(B + boff + (size_t)64 * 4096 + k0, lB + 2048);
    __syncthreads();
    short8 af[4], bfr[4];
#pragma unroll
    for (int fm = 0; fm < 4; ++fm)
      af[fm] = *(const short8*)(sA + (wm * 64 + fm * 16 + lm) * 32 + koff);
#pragma unroll
    for (int fn = 0; fn < 4; ++fn)
      bfr[fn] = *(const short8*)(sB + (wn * 64 + fn * 16 + lm) * 32 + koff);
#pragma unroll
    for (int fm = 0; fm < 4; ++fm)
#pragma unroll
      for (int fn = 0; fn < 4; ++fn)
        acc[fm][fn] = __builtin_amdgcn_mfma_f32_16x16x32_bf16(af[fm], bfr[fn],
                                                              acc[fm][fn], 0, 0, 0);
  }

  const int row_l = (l >> 4) * 4;
  ushort_t* pb = part + (size_t)kz * PART_STRIDE;
#pragma unroll
  for (int fm = 0; fm < 4; ++fm) {
#pragma unroll
    for (int fn = 0; fn < 4; ++fn) {
      const int n = nt * 128 + wn * 64 + fn * 16 + lm;
#pragma unroll
      for (int r = 0; r < 4; ++r) {
        const int m = mt * 128 + wm * 64 + fm * 16 + row_l + r;
        pb[(size_t)m * 6400 + n] = fb(acc[fm][fn][r]);
      }
    }
  }
}

// ---------------------------------------------------------------------------
// 3x3 conv GEMM (com/res) staging B DIRECTLY from NHWC ft40 (no im2col).
// ---------------------------------------------------------------------------
template <int MTILE, int KZ>
__global__ __launch_bounds__(256) void gemm_conv3(const ushort_t* __restrict__ A,
                                                  const ushort_t* __restrict__ ft,
                                                  const ushort_t* __restrict__ zp,
                                                  ushort_t* __restrict__ part,
                                                  int ksteps) {
  constexpr int FN = (MTILE == 128) ? 4 : 2;
  __shared__ ushort_t sA[MTILE * 32];
  __shared__ ushort_t sB[128 * 32];
  const int g = blockIdx.x;
  const int kz = g % KZ;
  const int r = g / KZ;
  const int mt = (MTILE == 128) ? (r & 1) : 0;
  const int nt = (MTILE == 128) ? (r >> 1) : r;
  const int t = threadIdx.x;
  const int wv = t >> 6, l = t & 63;
  const int wm = (MTILE == 128) ? (wv >> 1) : 0;
  const int wn = (MTILE == 128) ? (wv & 1) : wv;

  f4v acc[4][FN];
#pragma unroll
  for (int a = 0; a < 4; ++a)
#pragma unroll
    for (int bb = 0; bb < FN; ++bb) acc[a][bb] = (f4v)(0.f);

  const int ra = t >> 2;
  const int q  = ((t & 3) - (ra >> 1)) & 3;
  const int qc = q * 8;
  const size_t aoff = (size_t)(mt * MTILE + ra) * 2304 + qc;
  const int n0 = nt * 128 + ra;
  const int n1 = n0 + 64;
  const int b0 = n0 / 1600, p0 = n0 - b0 * 1600;
  const int b1 = n1 / 1600, p1 = n1 - b1 * 1600;
  const int ph0 = p0 / 40, pw0 = p0 - (p0 / 40) * 40;
  const int ph1 = p1 / 40, pw1 = p1 - (p1 / 40) * 40;
  const ushort_t* fp0 = ft + (size_t)n0 * 256 + qc;
  const ushort_t* fp1 = ft + (size_t)n1 * 256 + qc;
  ushort_t* lA = sA + t * 8;
  ushort_t* lB = sB + t * 8;

  int k0 = kz * ksteps * 32;
  const int lm = l & 15;
  const int koff = (((l >> 4) + (lm >> 1)) & 3) * 8;

  for (int step = 0; step < ksteps; ++step, k0 += 32) {
    const int tap = k0 >> 8, c0 = k0 & 255;
    const int ky = tap / 3;
    const int dy = ky - 1, dx = (tap - ky * 3) - 1;
    const int off = (dy * 40 + dx) * 256 + c0;
    const bool ok0 = ((unsigned)(ph0 + dy) < 40u) & ((unsigned)(pw0 + dx) < 40u);
    const bool ok1 = ((unsigned)(ph1 + dy) < 40u) & ((unsigned)(pw1 + dx) < 40u);
    const ushort_t* s0 = ok0 ? (fp0 + off) : zp;
    const ushort_t* s1 = ok1 ? (fp1 + off) : zp;
    __syncthreads();
    GLD16(A + aoff + k0, lA);
    if (MTILE == 128) GLD16(A + aoff + (size_t)64 * 2304 + k0, lA + 2048);
    GLD16(s0, lB);
    GLD16(s1, lB + 2048);
    __syncthreads();
    short8 af[4], bfr[FN];
#pragma unroll
    for (int fm = 0; fm < 4; ++fm)
      af[fm] = *(const short8*)(sA + (wm * 64 + fm * 16 + lm) * 32 + koff);
#pragma unroll
    for (int fn = 0; fn < FN; ++fn)
      bfr[fn] = *(const short8*)(sB + (wn * (16 * FN) + fn * 16 + lm) * 32 + koff);
#pragma unroll
    for (int fm = 0; fm < 4; ++fm)
#pragma unroll
      for (int fn = 0; fn < FN; ++fn)
        acc[fm][fn] = __builtin_amdgcn_mfma_f32_16x16x32_bf16(af[fm], bfr[fn],
                                                              acc[fm][fn], 0, 0, 0);
  }

  const int row_l = (l >> 4) * 4;
  ushort_t* pb = part + (size_t)kz * PART_STRIDE;
#pragma unroll
  for (int fm = 0; fm < 4; ++fm) {
#pragma unroll
    for (int fn = 0; fn < FN; ++fn) {
      const int n = nt * 128 + wn * (16 * FN) + fn * 16 + lm;
#pragma unroll
      for (int r = 0; r < 4; ++r) {
        const int m = mt * MTILE + wm * 64 + fm * 16 + row_l + r;
        pb[(size_t)m * 6400 + n] = fb(acc[fm][fn][r]);
      }
    }
  }
}

// ---------------------------------------------------------------------------
// Fused GEMM epilogue: dst_f32[NCHW] = (relu? max(sum8+bias,0):sum8+bias)+src
// and (if ft) ft40[NHWC] = bf16(dst) via LDS transpose -> the per-iter
// nhwc_bf16 kernel is eliminated (same fb() of the same f32 value).
// grid (25, 8, 4): p-tile 64, co-tile 32, batch. block 256.
// compute map: thread t -> co_l = t>>3 (32 co), pg = t&7 (8 p-octets).
// ft-write map: thread t -> p_l = t>>2 (64 p), cb = (t&3)*8 (32 co).
// ---------------------------------------------------------------------------
__global__ __launch_bounds__(256) void epi_fused(const ushort_t* __restrict__ part,
                                                 const float* __restrict__ bias,
                                                 const float* __restrict__ src,
                                                 float* __restrict__ dst,
                                                 ushort_t* __restrict__ ft, int relu) {
  __shared__ __align__(16) ushort_t tile[32][72];  // [co_l][p_l], stride 72 keeps 16B-aligned rows
  const int t = threadIdx.x;
  const int p0 = blockIdx.x * 64, c0 = blockIdx.y * 32, b = blockIdx.z;
  const int co_l = t >> 3, pg = t & 7;
  const int co = c0 + co_l;
  const size_t n = (size_t)b * 1600 + p0 + pg * 8;

  float a[8] = {0.f, 0.f, 0.f, 0.f, 0.f, 0.f, 0.f, 0.f};
#pragma unroll
  for (int kz = 0; kz < 8; ++kz) {
    short8 pp = *(const short8*)(part + (size_t)kz * PART_STRIDE + (size_t)co * 6400 + n);
#pragma unroll
    for (int j = 0; j < 8; ++j) a[j] += bu((ushort_t)pp[j]);
  }
  const float bv = bias[co];
  const size_t fo = ((size_t)b * 256 + co) * 1600 + p0 + pg * 8;
  float4 s0 = *(const float4*)(src + fo);
  float4 s1 = *(const float4*)(src + fo + 4);
  const float sv[8] = {s0.x, s0.y, s0.z, s0.w, s1.x, s1.y, s1.z, s1.w};
  float o[8];
#pragma unroll
  for (int j = 0; j < 8; ++j) {
    float v = a[j] + bv;
    if (relu) v = fmaxf(v, 0.f);
    o[j] = v + sv[j];
  }
  float4 o0 = {o[0], o[1], o[2], o[3]};
  float4 o1 = {o[4], o[5], o[6], o[7]};
  *(float4*)(dst + fo) = o0;
  *(float4*)(dst + fo + 4) = o1;

  if (ft) {
    short8 rr;
#pragma unroll
    for (int j = 0; j < 8; ++j) rr[j] = (short)fb(o[j]);
    *(short8*)(&tile[co_l][pg * 8]) = rr;
    __syncthreads();
    const int p_l = t >> 2, cb = (t & 3) * 8;
    short8 v;
#pragma unroll
    for (int j = 0; j < 8; ++j) v[j] = (short)tile[cb + j][p_l];
    *(short8*)(ft + ((size_t)(b * 1600 + p0 + p_l)) * 256 + c0 + cb) = v;
  }
}

// ---------------------------------------------------------------------------
extern "C" void kernel_launch(void* const* d_in, const int* in_sizes, int n_in,
                              void* d_out, int out_size, void* d_ws, size_t ws_size,
                              hipStream_t stream) {
  (void)in_sizes; (void)n_in; (void)out_size; (void)ws_size;
  const float* f0     = (const float*)d_in[0];
  const float* f1     = (const float*)d_in[1];
  const float* f2     = (const float*)d_in[2];
  const float* com_w0 = (const float*)d_in[3];
  const float* com_b0 = (const float*)d_in[4];
  const float* com_w1 = (const float*)d_in[5];
  const float* com_b1 = (const float*)d_in[6];
  const float* dcn_w0 = (const float*)d_in[7];
  const float* dcn_b0 = (const float*)d_in[8];
  const float* dcn_w1 = (const float*)d_in[9];
  const float* dcn_b1 = (const float*)d_in[10];
  const float* res_w  = (const float*)d_in[11];
  const float* res_b  = (const float*)d_in[12];
  float* out = (float*)d_out;
  float* ws  = (float*)d_ws;

  // ws layout (float offsets); ~40.3M floats ~= 161 MB
  float*    fbuf  = ws + 0;          // 1,638,400 f32
  ushort_t* A0    = (ushort_t*)(ws + 1700000);   // 1,048,576 u16
  ushort_t* A1    = (ushort_t*)(ws + 2230000);   // 1,048,576 u16
  ushort_t* Acom0 = (ushort_t*)(ws + 2760000);   //   147,456 u16 (64x2304)
  ushort_t* Acom1 = (ushort_t*)(ws + 2840000);   //   147,456 u16
  ushort_t* Ares  = (ushort_t*)(ws + 2920000);   //   589,824 u16 (256x2304)
  ushort_t* ft40  = (ushort_t*)(ws + 3220000);   // 1,638,400 u16
  ushort_t* f1t   = (ushort_t*)(ws + 4050000);   // 6,553,600 u16
  ushort_t* f0t   = (ushort_t*)(ws + 7330000);   // 26,214,400 u16
  ushort_t* colT  = (ushort_t*)(ws + 20440000);  // 26,214,400 u16
  ushort_t* part  = (ushort_t*)(ws + 33550000);  // 13,107,200 u16 (8 bf16 slices)
  ushort_t* zp    = (ushort_t*)(ws + 40110000);  //       256 u16 zero page

  // 2 prep launches (was 6): weights+zp, then all three NHWC conversions
  prep_all<<<3969, 256, 0, stream>>>(com_w0, com_w1, res_w, dcn_w0, dcn_w1,
                                     Acom0, Acom1, Ares, A0, A1, zp);
  nhwc_all<<<dim3(1050, 8, 4), 256, 0, stream>>>(f2, f1, f0, ft40, f1t, f0t);

  const float* fsrc = f2;
  for (int s = 0; s < 4; ++s) {
    int l = s & 1;
    // com conv as GEMM (M=48 pad 64, K=2304, split-K 8 -> 400 blocks for CU fill)
    gemm_conv3<64, 8><<<400, 256, 0, stream>>>(l ? Acom1 : Acom0, ft40, zp, part, 9);
    // sampler fuses com epilogue (bias + partial-sum + sigmoid)
    if (l == 0) {
      sample_kernel<<<800, 256, 0, stream>>>(f1t, part, com_b0, colT, 80, 80, 2, 1, 1);
    } else {
      sample_kernel<<<800, 256, 0, stream>>>(f0t, part, com_b1, colT, 160, 160, 4, 3, 3);
    }
    // deformable conv GEMM (K=4096, split-K 8)
    gemm_deform<<<800, 256, 0, stream>>>(l ? A1 : A0, colT, part);
    // fused epilogue writes fbuf (f32 NCHW) AND ft40 (bf16 NHWC) for next stage
    epi_fused<<<dim3(25, 8, 4), 256, 0, stream>>>(part, l ? dcn_b1 : dcn_b0, fsrc,
                                                  fbuf, ft40, 1);
    fsrc = fbuf;
  }
  // res conv as GEMM (M=256, K=2304, split-K 8); ft40 already written by epi_fused
  gemm_conv3<128, 8><<<800, 256, 0, stream>>>(Ares, ft40, zp, part, 9);
  epi_fused<<<dim3(25, 8, 4), 256, 0, stream>>>(part, res_b, f2, out, nullptr, 0);
}

// Round 3
// 539.618 us; speedup vs baseline: 1.0522x; 1.0355x over previous
//
#include <hip/hip_runtime.h>

#define HW40 1600
typedef unsigned short ushort_t;
typedef __attribute__((ext_vector_type(8))) short short8;
typedef __attribute__((ext_vector_type(4))) short short4v;
typedef __attribute__((ext_vector_type(4))) float f4v;

__device__ __forceinline__ float bu(ushort_t u) {
  union { unsigned i; float f; } x; x.i = ((unsigned)u) << 16; return x.f;
}
__device__ __forceinline__ ushort_t fb(float f) {
  union { float f; unsigned i; } x; x.f = f;
  unsigned r = x.i + 0x7FFFu + ((x.i >> 16) & 1u);
  return (ushort_t)(r >> 16);
}

#define GLD16(g, l)                                                            \
  __builtin_amdgcn_global_load_lds(                                            \
      (const __attribute__((address_space(1))) void*)(g),                      \
      (__attribute__((address_space(3))) void*)(l), 16, 0, 0)

#define PART_STRIDE 1638400  // one split-K slice: 256 x 6400

// ---------------------------------------------------------------------------
// Merged prep: zero page + 3x convert_w9 + convert_dcnw in ONE launch.
// ---------------------------------------------------------------------------
__global__ __launch_bounds__(256) void prep_all(
    const float* __restrict__ com_w0, const float* __restrict__ com_w1,
    const float* __restrict__ res_w, const float* __restrict__ dcn_w0,
    const float* __restrict__ dcn_w1, ushort_t* __restrict__ Acom0,
    ushort_t* __restrict__ Acom1, ushort_t* __restrict__ Ares,
    ushort_t* __restrict__ A0, ushort_t* __restrict__ A1,
    ushort_t* __restrict__ zp) {
  __shared__ float s[4096];
  const int g = blockIdx.x;
  const int t = threadIdx.x;
  if (g < 3456) {
    // 3x3 conv weights [co][cin][3][3] fp32 -> A[co][tap*256+cin] bf16
    const float* src; ushort_t* dst; int Cout_src; int base;
    if (g < 576)       { src = com_w0; dst = Acom0; Cout_src = 48;  base = g; }
    else if (g < 1152) { src = com_w1; dst = Acom1; Cout_src = 48;  base = g - 576; }
    else               { src = res_w;  dst = Ares;  Cout_src = 256; base = g - 1152; }
    const int idx = base * 256 + t;
    const int co = idx / 2304;
    const int k  = idx - co * 2304;
    const int cin = k & 255, tap = k >> 8;
    dst[idx] = (co < Cout_src) ? fb(src[(size_t)co * 2304 + cin * 9 + tap]) : (ushort_t)0;
  } else if (g < 3968) {
    // dcn weights [co][cin][16] fp32 -> A_bf16 [co][k = i*256 + cin]
    const int lg = g - 3456;
    const int co = lg & 255;
    const float* w = (lg < 256) ? dcn_w0 : dcn_w1;
    ushort_t* A = (lg < 256) ? A0 : A1;
    const float4* wp = (const float4*)(w + (size_t)co * 4096);
#pragma unroll
    for (int q = 0; q < 4; ++q) ((float4*)s)[t + q * 256] = wp[t + q * 256];
    __syncthreads();
    const int i = t >> 4, cb = (t & 15) * 16;
    ushort_t tmp[16];
#pragma unroll
    for (int j = 0; j < 16; ++j) tmp[j] = fb(s[(cb + j) * 16 + i]);
    ushort_t* op = A + (size_t)co * 4096 + t * 16;
    ((uint4*)op)[0] = ((uint4*)tmp)[0];
    ((uint4*)op)[1] = ((uint4*)tmp)[1];
  } else {
    zp[t] = 0;  // zero page for OOB conv taps
  }
}

// ---------------------------------------------------------------------------
// Merged NCHW fp32 -> NHWC bf16 (v2): 32-spatial x 256-channel tile/block.
// Loads: float4 per lane (128B segments, 4 channels per lane-group with
// register transpose). LDS bf16 tile [32][264] (row 528B, 16B-aligned,
// odd word-parity pad). Stores: contiguous full-row ds_read_b128 ->
// short8 global = 512B write segments.
// grid x: [0,50) f2 | [50,250) f1 | [250,1050) f0; z = batch. y unused.
// ---------------------------------------------------------------------------
__global__ __launch_bounds__(256) void nhwc_all(const float* __restrict__ f2,
                                                const float* __restrict__ f1,
                                                const float* __restrict__ f0,
                                                ushort_t* __restrict__ ft40,
                                                ushort_t* __restrict__ f1t,
                                                ushort_t* __restrict__ f0t) {
  __shared__ __align__(16) ushort_t tile[32][264];
  const int gx = blockIdx.x;
  const float* x; ushort_t* xt; int HW, sblk;
  if (gx < 50)       { x = f2; xt = ft40; HW = 1600;  sblk = gx; }
  else if (gx < 250) { x = f1; xt = f1t;  HW = 6400;  sblk = gx - 50; }
  else               { x = f0; xt = f0t;  HW = 25600; sblk = gx - 250; }
  const int s0 = sblk * 32, b = blockIdx.z;
  const int t = threadIdx.x;
  const int sp4 = (t & 7) * 4;     // 4 consecutive spatial per lane
  const int cbase = (t >> 3) * 4;  // 4 consecutive channels per lane
  const float* xb = x + (size_t)b * 256 * HW + s0 + sp4;
#pragma unroll
  for (int q = 0; q < 2; ++q) {
    const int cc = cbase + q * 128;
    const float4 v0 = *(const float4*)(xb + (size_t)(cc + 0) * HW);
    const float4 v1 = *(const float4*)(xb + (size_t)(cc + 1) * HW);
    const float4 v2 = *(const float4*)(xb + (size_t)(cc + 2) * HW);
    const float4 v3 = *(const float4*)(xb + (size_t)(cc + 3) * HW);
    // register transpose: 4 channels x 4 spatial -> per-spatial short4
    ushort_t p0[4] = {fb(v0.x), fb(v1.x), fb(v2.x), fb(v3.x)};
    ushort_t p1[4] = {fb(v0.y), fb(v1.y), fb(v2.y), fb(v3.y)};
    ushort_t p2[4] = {fb(v0.z), fb(v1.z), fb(v2.z), fb(v3.z)};
    ushort_t p3[4] = {fb(v0.w), fb(v1.w), fb(v2.w), fb(v3.w)};
    *(short4v*)(&tile[sp4 + 0][cc]) = *(short4v*)p0;
    *(short4v*)(&tile[sp4 + 1][cc]) = *(short4v*)p1;
    *(short4v*)(&tile[sp4 + 2][cc]) = *(short4v*)p2;
    *(short4v*)(&tile[sp4 + 3][cc]) = *(short4v*)p3;
  }
  __syncthreads();
  const int c8 = (t & 31) * 8;
  const int spb = t >> 5;
  ushort_t* ob = xt + ((size_t)b * HW + s0) * 256;
#pragma unroll
  for (int q2 = 0; q2 < 4; ++q2) {
    const int sp = spb + q2 * 8;
    short8 v = *(const short8*)(&tile[sp][c8]);
    *(short8*)(ob + (size_t)sp * 256 + c8) = v;
  }
}

// ---------------------------------------------------------------------------
// Sampler (fused com-epilogue). XCD-contiguous work swizzle: 1D grid 800,
// work = (g&7)*100 + (g>>3). 8-px tiles, block 256. Sums 8 split-K slices
// (com conv split-K 8).
// ---------------------------------------------------------------------------
__global__ __launch_bounds__(256) void sample_kernel(
    const ushort_t* __restrict__ xt, const ushort_t* __restrict__ part,
    const float* __restrict__ cbias, ushort_t* __restrict__ colT,
    int Hin, int Win, int stride, int pad, int dil) {
  __shared__ int4  gL[128];
  __shared__ float4 gW[128];
  const int g = blockIdx.x;
  const int work = (g & 7) * 100 + (g >> 3);
  const int b = work / 200;
  const int px0 = (work - b * 200) * 8;
  const int t = threadIdx.x;
  const int HWin = Hin * Win;

  if (t < 128) {  // geometry: pair pid = t -> (px_l = t&7, tap i = t>>3)
    const int px_l = t & 7, i = t >> 3;
    const int p = px0 + px_l;
    const int n = b * 1600 + p;
    const int ph = p / 40, pw = p - (p / 40) * 40;
    float dy = cbias[2 * i], dx = cbias[2 * i + 1], mzr = cbias[32 + i];
#pragma unroll
    for (int kz = 0; kz < 8; ++kz) {
      const ushort_t* pp = part + (size_t)kz * PART_STRIDE + n;
      dy  += bu(pp[(size_t)(2 * i) * 6400]);
      dx  += bu(pp[(size_t)(2 * i + 1) * 6400]);
      mzr += bu(pp[(size_t)(32 + i) * 6400]);
    }
    float mz = 1.f / (1.f + expf(-mzr));
    float py = (float)(ph * stride - pad + (i >> 2) * dil) + dy;
    float px = (float)(pw * stride - pad + (i & 3) * dil) + dx;
    float y0f = floorf(py), x0f = floorf(px);
    float ly = py - y0f, lx = px - x0f;
    int y0 = (int)y0f, x0 = (int)x0f;
    int y1 = y0 + 1, x1 = x0 + 1;
    float hy = 1.f - ly, hx = 1.f - lx;
    float w00 = hy * hx * mz, w01 = hy * lx * mz;
    float w10 = ly * hx * mz, w11 = ly * lx * mz;
    if (y0 < 0 || y0 >= Hin) { w00 = 0.f; w01 = 0.f; }
    if (y1 < 0 || y1 >= Hin) { w10 = 0.f; w11 = 0.f; }
    if (x0 < 0 || x0 >= Win) { w00 = 0.f; w10 = 0.f; }
    if (x1 < 0 || x1 >= Win) { w01 = 0.f; w11 = 0.f; }
    int cy0 = min(max(y0, 0), Hin - 1), cy1 = min(max(y1, 0), Hin - 1);
    int cx0 = min(max(x0, 0), Win - 1), cx1 = min(max(x1, 0), Win - 1);
    gL[t] = make_int4((cy0 * Win + cx0) * 256, (cy0 * Win + cx1) * 256,
                      (cy1 * Win + cx0) * 256, (cy1 * Win + cx1) * 256);
    gW[t] = make_float4(w00, w01, w10, w11);
  }
  __syncthreads();

  const ushort_t* xtb = xt + (size_t)b * HWin * 256;
  const int wv = t >> 6, l = t & 63;
  const int half = l >> 5;
  const int cin8 = (l & 31) * 8;

#pragma unroll 2
  for (int it = 0; it < 16; ++it) {
    const int pr = it * 8 + wv * 2 + half;
    const int4 G = gL[pr];
    const float4 W = gW[pr];
    short8 c00 = *(const short8*)(xtb + G.x + cin8);
    short8 c01 = *(const short8*)(xtb + G.y + cin8);
    short8 c10 = *(const short8*)(xtb + G.z + cin8);
    short8 c11 = *(const short8*)(xtb + G.w + cin8);
    short8 rr;
#pragma unroll
    for (int j = 0; j < 8; ++j) {
      float v = W.x * bu((ushort_t)c00[j]) + W.y * bu((ushort_t)c01[j]) +
                W.z * bu((ushort_t)c10[j]) + W.w * bu((ushort_t)c11[j]);
      rr[j] = (short)fb(v);
    }
    const int px_l = pr & 7, i = pr >> 3;
    *(short8*)(colT + ((size_t)(b * 1600 + px0 + px_l) * 4096 + i * 256 + cin8)) = rr;
  }
}

// ---------------------------------------------------------------------------
// Deform GEMM (K=4096, colT B-matrix), split-K 4, bf16 partials.
// grid 400: kz=g&3, mt=(g>>2)&1, nt=g>>3. 32 K-steps per block.
// ---------------------------------------------------------------------------
__global__ __launch_bounds__(256) void gemm_deform(const ushort_t* __restrict__ A,
                                                   const ushort_t* __restrict__ B,
                                                   ushort_t* __restrict__ part) {
  __shared__ ushort_t sA[128 * 32];
  __shared__ ushort_t sB[128 * 32];
  const int g = blockIdx.x;
  const int kz = g & 3, mt = (g >> 2) & 1, nt = g >> 3;
  const int t = threadIdx.x;
  const int wv = t >> 6, l = t & 63;
  const int wm = wv >> 1, wn = wv & 1;

  f4v acc[4][4];
#pragma unroll
  for (int a = 0; a < 4; ++a)
#pragma unroll
    for (int bb = 0; bb < 4; ++bb) acc[a][bb] = (f4v)(0.f);

  const int ra = t >> 2;
  const int q  = ((t & 3) - (ra >> 1)) & 3;
  const size_t aoff = (size_t)(mt * 128 + ra) * 4096 + q * 8;
  const size_t boff = (size_t)(nt * 128 + ra) * 4096 + q * 8;
  ushort_t* lA = sA + t * 8;
  ushort_t* lB = sB + t * 8;

  int k0 = kz * 1024;
  const int lm = l & 15;
  const int koff = (((l >> 4) + (lm >> 1)) & 3) * 8;

  for (int step = 0; step < 32; ++step, k0 += 32) {
    __syncthreads();
    GLD16(A + aoff + k0, lA);
    GLD16(A + aoff + (size_t)64 * 4096 + k0, lA + 2048);
    GLD16(B + boff + k0, lB);
    GLD16(B + boff + (size_t)64 * 4096 + k0, lB + 2048);
    __syncthreads();
    short8 af[4], bfr[4];
#pragma unroll
    for (int fm = 0; fm < 4; ++fm)
      af[fm] = *(const short8*)(sA + (wm * 64 + fm * 16 + lm) * 32 + koff);
#pragma unroll
    for (int fn = 0; fn < 4; ++fn)
      bfr[fn] = *(const short8*)(sB + (wn * 64 + fn * 16 + lm) * 32 + koff);
#pragma unroll
    for (int fm = 0; fm < 4; ++fm)
#pragma unroll
      for (int fn = 0; fn < 4; ++fn)
        acc[fm][fn] = __builtin_amdgcn_mfma_f32_16x16x32_bf16(af[fm], bfr[fn],
                                                              acc[fm][fn], 0, 0, 0);
  }

  const int row_l = (l >> 4) * 4;
  ushort_t* pb = part + (size_t)kz * PART_STRIDE;
#pragma unroll
  for (int fm = 0; fm < 4; ++fm) {
#pragma unroll
    for (int fn = 0; fn < 4; ++fn) {
      const int n = nt * 128 + wn * 64 + fn * 16 + lm;
#pragma unroll
      for (int r = 0; r < 4; ++r) {
        const int m = mt * 128 + wm * 64 + fm * 16 + row_l + r;
        pb[(size_t)m * 6400 + n] = fb(acc[fm][fn][r]);
      }
    }
  }
}

// ---------------------------------------------------------------------------
// 3x3 conv GEMM (com/res) staging B DIRECTLY from NHWC ft40 (no im2col).
// ---------------------------------------------------------------------------
template <int MTILE, int KZ>
__global__ __launch_bounds__(256) void gemm_conv3(const ushort_t* __restrict__ A,
                                                  const ushort_t* __restrict__ ft,
                                                  const ushort_t* __restrict__ zp,
                                                  ushort_t* __restrict__ part,
                                                  int ksteps) {
  constexpr int FN = (MTILE == 128) ? 4 : 2;
  __shared__ ushort_t sA[MTILE * 32];
  __shared__ ushort_t sB[128 * 32];
  const int g = blockIdx.x;
  const int kz = g % KZ;
  const int r = g / KZ;
  const int mt = (MTILE == 128) ? (r & 1) : 0;
  const int nt = (MTILE == 128) ? (r >> 1) : r;
  const int t = threadIdx.x;
  const int wv = t >> 6, l = t & 63;
  const int wm = (MTILE == 128) ? (wv >> 1) : 0;
  const int wn = (MTILE == 128) ? (wv & 1) : wv;

  f4v acc[4][FN];
#pragma unroll
  for (int a = 0; a < 4; ++a)
#pragma unroll
    for (int bb = 0; bb < FN; ++bb) acc[a][bb] = (f4v)(0.f);

  const int ra = t >> 2;
  const int q  = ((t & 3) - (ra >> 1)) & 3;
  const int qc = q * 8;
  const size_t aoff = (size_t)(mt * MTILE + ra) * 2304 + qc;
  const int n0 = nt * 128 + ra;
  const int n1 = n0 + 64;
  const int b0 = n0 / 1600, p0 = n0 - b0 * 1600;
  const int b1 = n1 / 1600, p1 = n1 - b1 * 1600;
  const int ph0 = p0 / 40, pw0 = p0 - (p0 / 40) * 40;
  const int ph1 = p1 / 40, pw1 = p1 - (p1 / 40) * 40;
  const ushort_t* fp0 = ft + (size_t)n0 * 256 + qc;
  const ushort_t* fp1 = ft + (size_t)n1 * 256 + qc;
  ushort_t* lA = sA + t * 8;
  ushort_t* lB = sB + t * 8;

  int k0 = kz * ksteps * 32;
  const int lm = l & 15;
  const int koff = (((l >> 4) + (lm >> 1)) & 3) * 8;

  for (int step = 0; step < ksteps; ++step, k0 += 32) {
    const int tap = k0 >> 8, c0 = k0 & 255;
    const int ky = tap / 3;
    const int dy = ky - 1, dx = (tap - ky * 3) - 1;
    const int off = (dy * 40 + dx) * 256 + c0;
    const bool ok0 = ((unsigned)(ph0 + dy) < 40u) & ((unsigned)(pw0 + dx) < 40u);
    const bool ok1 = ((unsigned)(ph1 + dy) < 40u) & ((unsigned)(pw1 + dx) < 40u);
    const ushort_t* s0 = ok0 ? (fp0 + off) : zp;
    const ushort_t* s1 = ok1 ? (fp1 + off) : zp;
    __syncthreads();
    GLD16(A + aoff + k0, lA);
    if (MTILE == 128) GLD16(A + aoff + (size_t)64 * 2304 + k0, lA + 2048);
    GLD16(s0, lB);
    GLD16(s1, lB + 2048);
    __syncthreads();
    short8 af[4], bfr[FN];
#pragma unroll
    for (int fm = 0; fm < 4; ++fm)
      af[fm] = *(const short8*)(sA + (wm * 64 + fm * 16 + lm) * 32 + koff);
#pragma unroll
    for (int fn = 0; fn < FN; ++fn)
      bfr[fn] = *(const short8*)(sB + (wn * (16 * FN) + fn * 16 + lm) * 32 + koff);
#pragma unroll
    for (int fm = 0; fm < 4; ++fm)
#pragma unroll
      for (int fn = 0; fn < FN; ++fn)
        acc[fm][fn] = __builtin_amdgcn_mfma_f32_16x16x32_bf16(af[fm], bfr[fn],
                                                              acc[fm][fn], 0, 0, 0);
  }

  const int row_l = (l >> 4) * 4;
  ushort_t* pb = part + (size_t)kz * PART_STRIDE;
#pragma unroll
  for (int fm = 0; fm < 4; ++fm) {
#pragma unroll
    for (int fn = 0; fn < FN; ++fn) {
      const int n = nt * 128 + wn * (16 * FN) + fn * 16 + lm;
#pragma unroll
      for (int r = 0; r < 4; ++r) {
        const int m = mt * MTILE + wm * 64 + fm * 16 + row_l + r;
        pb[(size_t)m * 6400 + n] = fb(acc[fm][fn][r]);
      }
    }
  }
}

// ---------------------------------------------------------------------------
// Fused GEMM epilogue (NKZ split-K slices):
// dst_f32[NCHW] = (relu? max(sum+bias,0):sum+bias)+src, and (if ft)
// ft40[NHWC] = bf16(dst) via LDS transpose.
// grid (25, 8, 4): p-tile 64, co-tile 32, batch. block 256.
// ---------------------------------------------------------------------------
template <int NKZ>
__global__ __launch_bounds__(256) void epi_fused(const ushort_t* __restrict__ part,
                                                 const float* __restrict__ bias,
                                                 const float* __restrict__ src,
                                                 float* __restrict__ dst,
                                                 ushort_t* __restrict__ ft, int relu) {
  __shared__ __align__(16) ushort_t tile[32][72];  // [co_l][p_l]
  const int t = threadIdx.x;
  const int p0 = blockIdx.x * 64, c0 = blockIdx.y * 32, b = blockIdx.z;
  const int co_l = t >> 3, pg = t & 7;
  const int co = c0 + co_l;
  const size_t n = (size_t)b * 1600 + p0 + pg * 8;

  float a[8] = {0.f, 0.f, 0.f, 0.f, 0.f, 0.f, 0.f, 0.f};
#pragma unroll
  for (int kz = 0; kz < NKZ; ++kz) {
    short8 pp = *(const short8*)(part + (size_t)kz * PART_STRIDE + (size_t)co * 6400 + n);
#pragma unroll
    for (int j = 0; j < 8; ++j) a[j] += bu((ushort_t)pp[j]);
  }
  const float bv = bias[co];
  const size_t fo = ((size_t)b * 256 + co) * 1600 + p0 + pg * 8;
  float4 s0 = *(const float4*)(src + fo);
  float4 s1 = *(const float4*)(src + fo + 4);
  const float sv[8] = {s0.x, s0.y, s0.z, s0.w, s1.x, s1.y, s1.z, s1.w};
  float o[8];
#pragma unroll
  for (int j = 0; j < 8; ++j) {
    float v = a[j] + bv;
    if (relu) v = fmaxf(v, 0.f);
    o[j] = v + sv[j];
  }
  float4 o0 = {o[0], o[1], o[2], o[3]};
  float4 o1 = {o[4], o[5], o[6], o[7]};
  *(float4*)(dst + fo) = o0;
  *(float4*)(dst + fo + 4) = o1;

  if (ft) {
    short8 rr;
#pragma unroll
    for (int j = 0; j < 8; ++j) rr[j] = (short)fb(o[j]);
    *(short8*)(&tile[co_l][pg * 8]) = rr;
    __syncthreads();
    const int p_l = t >> 2, cb = (t & 3) * 8;
    short8 v;
#pragma unroll
    for (int j = 0; j < 8; ++j) v[j] = (short)tile[cb + j][p_l];
    *(short8*)(ft + ((size_t)(b * 1600 + p0 + p_l)) * 256 + c0 + cb) = v;
  }
}

// ---------------------------------------------------------------------------
extern "C" void kernel_launch(void* const* d_in, const int* in_sizes, int n_in,
                              void* d_out, int out_size, void* d_ws, size_t ws_size,
                              hipStream_t stream) {
  (void)in_sizes; (void)n_in; (void)out_size; (void)ws_size;
  const float* f0     = (const float*)d_in[0];
  const float* f1     = (const float*)d_in[1];
  const float* f2     = (const float*)d_in[2];
  const float* com_w0 = (const float*)d_in[3];
  const float* com_b0 = (const float*)d_in[4];
  const float* com_w1 = (const float*)d_in[5];
  const float* com_b1 = (const float*)d_in[6];
  const float* dcn_w0 = (const float*)d_in[7];
  const float* dcn_b0 = (const float*)d_in[8];
  const float* dcn_w1 = (const float*)d_in[9];
  const float* dcn_b1 = (const float*)d_in[10];
  const float* res_w  = (const float*)d_in[11];
  const float* res_b  = (const float*)d_in[12];
  float* out = (float*)d_out;
  float* ws  = (float*)d_ws;

  // ws layout (float offsets); ~40.3M floats ~= 161 MB
  float*    fbuf  = ws + 0;          // 1,638,400 f32
  ushort_t* A0    = (ushort_t*)(ws + 1700000);   // 1,048,576 u16
  ushort_t* A1    = (ushort_t*)(ws + 2230000);   // 1,048,576 u16
  ushort_t* Acom0 = (ushort_t*)(ws + 2760000);   //   147,456 u16 (64x2304)
  ushort_t* Acom1 = (ushort_t*)(ws + 2840000);   //   147,456 u16
  ushort_t* Ares  = (ushort_t*)(ws + 2920000);   //   589,824 u16 (256x2304)
  ushort_t* ft40  = (ushort_t*)(ws + 3220000);   // 1,638,400 u16
  ushort_t* f1t   = (ushort_t*)(ws + 4050000);   // 6,553,600 u16
  ushort_t* f0t   = (ushort_t*)(ws + 7330000);   // 26,214,400 u16
  ushort_t* colT  = (ushort_t*)(ws + 20440000);  // 26,214,400 u16
  ushort_t* part  = (ushort_t*)(ws + 33550000);  // 13,107,200 u16 (8 bf16 slices)
  ushort_t* zp    = (ushort_t*)(ws + 40110000);  //       256 u16 zero page

  // 2 prep launches: weights+zp, then all three NHWC conversions (v2 tiles)
  prep_all<<<3969, 256, 0, stream>>>(com_w0, com_w1, res_w, dcn_w0, dcn_w1,
                                     Acom0, Acom1, Ares, A0, A1, zp);
  nhwc_all<<<dim3(1050, 1, 4), 256, 0, stream>>>(f2, f1, f0, ft40, f1t, f0t);

  const float* fsrc = f2;
  for (int s = 0; s < 4; ++s) {
    int l = s & 1;
    // com conv as GEMM (M=48 pad 64, K=2304, split-K 8 -> 400 blocks)
    gemm_conv3<64, 8><<<400, 256, 0, stream>>>(l ? Acom1 : Acom0, ft40, zp, part, 9);
    // sampler fuses com epilogue (bias + partial-sum + sigmoid)
    if (l == 0) {
      sample_kernel<<<800, 256, 0, stream>>>(f1t, part, com_b0, colT, 80, 80, 2, 1, 1);
    } else {
      sample_kernel<<<800, 256, 0, stream>>>(f0t, part, com_b1, colT, 160, 160, 4, 3, 3);
    }
    // deformable conv GEMM (K=4096, split-K 4)
    gemm_deform<<<400, 256, 0, stream>>>(l ? A1 : A0, colT, part);
    // fused epilogue writes fbuf (f32 NCHW) AND ft40 (bf16 NHWC) for next stage
    epi_fused<4><<<dim3(25, 8, 4), 256, 0, stream>>>(part, l ? dcn_b1 : dcn_b0, fsrc,
                                                     fbuf, ft40, 1);
    fsrc = fbuf;
  }
  // res conv as GEMM (M=256, K=2304, split-K 8); ft40 already written by epi_fused
  gemm_conv3<128, 8><<<800, 256, 0, stream>>>(Ares, ft40, zp, part, 9);
  epi_fused<8><<<dim3(25, 8, 4), 256, 0, stream>>>(part, res_b, f2, out, nullptr, 0);
}

// Round 4
// 525.168 us; speedup vs baseline: 1.0812x; 1.0275x over previous
//
#include <hip/hip_runtime.h>

#define HW40 1600
typedef unsigned short ushort_t;
typedef __attribute__((ext_vector_type(8))) short short8;
typedef __attribute__((ext_vector_type(4))) short short4v;
typedef __attribute__((ext_vector_type(4))) float f4v;

__device__ __forceinline__ float bu(ushort_t u) {
  union { unsigned i; float f; } x; x.i = ((unsigned)u) << 16; return x.f;
}
__device__ __forceinline__ ushort_t fb(float f) {
  union { float f; unsigned i; } x; x.f = f;
  unsigned r = x.i + 0x7FFFu + ((x.i >> 16) & 1u);
  return (ushort_t)(r >> 16);
}

#define GLD16(g, l)                                                            \
  __builtin_amdgcn_global_load_lds(                                            \
      (const __attribute__((address_space(1))) void*)(g),                      \
      (__attribute__((address_space(3))) void*)(l), 16, 0, 0)

#define PART_STRIDE 1638400  // one split-K slice: 256 x 6400

// ---------------------------------------------------------------------------
// Merged prep: zero page + 3x convert_w9 + convert_dcnw in ONE launch.
// ---------------------------------------------------------------------------
__global__ __launch_bounds__(256) void prep_all(
    const float* __restrict__ com_w0, const float* __restrict__ com_w1,
    const float* __restrict__ res_w, const float* __restrict__ dcn_w0,
    const float* __restrict__ dcn_w1, ushort_t* __restrict__ Acom0,
    ushort_t* __restrict__ Acom1, ushort_t* __restrict__ Ares,
    ushort_t* __restrict__ A0, ushort_t* __restrict__ A1,
    ushort_t* __restrict__ zp) {
  __shared__ float s[4096];
  const int g = blockIdx.x;
  const int t = threadIdx.x;
  if (g < 3456) {
    // 3x3 conv weights [co][cin][3][3] fp32 -> A[co][tap*256+cin] bf16
    const float* src; ushort_t* dst; int Cout_src; int base;
    if (g < 576)       { src = com_w0; dst = Acom0; Cout_src = 48;  base = g; }
    else if (g < 1152) { src = com_w1; dst = Acom1; Cout_src = 48;  base = g - 576; }
    else               { src = res_w;  dst = Ares;  Cout_src = 256; base = g - 1152; }
    const int idx = base * 256 + t;
    const int co = idx / 2304;
    const int k  = idx - co * 2304;
    const int cin = k & 255, tap = k >> 8;
    dst[idx] = (co < Cout_src) ? fb(src[(size_t)co * 2304 + cin * 9 + tap]) : (ushort_t)0;
  } else if (g < 3968) {
    // dcn weights [co][cin][16] fp32 -> A_bf16 [co][k = i*256 + cin]
    const int lg = g - 3456;
    const int co = lg & 255;
    const float* w = (lg < 256) ? dcn_w0 : dcn_w1;
    ushort_t* A = (lg < 256) ? A0 : A1;
    const float4* wp = (const float4*)(w + (size_t)co * 4096);
#pragma unroll
    for (int q = 0; q < 4; ++q) ((float4*)s)[t + q * 256] = wp[t + q * 256];
    __syncthreads();
    const int i = t >> 4, cb = (t & 15) * 16;
    ushort_t tmp[16];
#pragma unroll
    for (int j = 0; j < 16; ++j) tmp[j] = fb(s[(cb + j) * 16 + i]);
    ushort_t* op = A + (size_t)co * 4096 + t * 16;
    ((uint4*)op)[0] = ((uint4*)tmp)[0];
    ((uint4*)op)[1] = ((uint4*)tmp)[1];
  } else {
    zp[t] = 0;  // zero page for OOB conv taps
  }
}

// ---------------------------------------------------------------------------
// Merged NCHW fp32 -> NHWC bf16 (v3): two 32-spatial x 256-ch tiles per block,
// all 16 float4 loads issued up-front (deep MLP), double LDS buffer, ONE
// barrier total. grid x: [0,25) f2 | [25,125) f1 | [125,525) f0; z = batch.
// ---------------------------------------------------------------------------
__global__ __launch_bounds__(256) void nhwc_all(const float* __restrict__ f2,
                                                const float* __restrict__ f1,
                                                const float* __restrict__ f0,
                                                ushort_t* __restrict__ ft40,
                                                ushort_t* __restrict__ f1t,
                                                ushort_t* __restrict__ f0t) {
  __shared__ __align__(16) ushort_t tA[32][264];
  __shared__ __align__(16) ushort_t tB[32][264];
  const int gx = blockIdx.x;
  const float* x; ushort_t* xt; int HW, sblk;
  if (gx < 25)       { x = f2; xt = ft40; HW = 1600;  sblk = gx * 2; }
  else if (gx < 125) { x = f1; xt = f1t;  HW = 6400;  sblk = (gx - 25) * 2; }
  else               { x = f0; xt = f0t;  HW = 25600; sblk = (gx - 125) * 2; }
  const int b = blockIdx.z;
  const int t = threadIdx.x;
  const int sp4 = (t & 7) * 4;     // 4 consecutive spatial per lane
  const int cbase = (t >> 3) * 4;  // 4 consecutive channels per lane
  const float* xb0 = x + (size_t)b * 256 * HW + sblk * 32 + sp4;

  // issue ALL loads first (tile0 then tile1) -> 16 dwordx4 in flight
  float4 v[2][2][4];
#pragma unroll
  for (int k = 0; k < 2; ++k)
#pragma unroll
    for (int q = 0; q < 2; ++q) {
      const int cc = cbase + q * 128;
      const float* bp = xb0 + k * 32;
#pragma unroll
      for (int j = 0; j < 4; ++j)
        v[k][q][j] = *(const float4*)(bp + (size_t)(cc + j) * HW);
    }

  // register transpose 4ch x 4sp -> per-spatial short4, into LDS (A then B)
#pragma unroll
  for (int k = 0; k < 2; ++k) {
    ushort_t (*tile)[264] = k ? tB : tA;
#pragma unroll
    for (int q = 0; q < 2; ++q) {
      const int cc = cbase + q * 128;
      const float4 v0 = v[k][q][0], v1 = v[k][q][1];
      const float4 v2 = v[k][q][2], v3 = v[k][q][3];
      ushort_t p0[4] = {fb(v0.x), fb(v1.x), fb(v2.x), fb(v3.x)};
      ushort_t p1[4] = {fb(v0.y), fb(v1.y), fb(v2.y), fb(v3.y)};
      ushort_t p2[4] = {fb(v0.z), fb(v1.z), fb(v2.z), fb(v3.z)};
      ushort_t p3[4] = {fb(v0.w), fb(v1.w), fb(v2.w), fb(v3.w)};
      *(short4v*)(&tile[sp4 + 0][cc]) = *(short4v*)p0;
      *(short4v*)(&tile[sp4 + 1][cc]) = *(short4v*)p1;
      *(short4v*)(&tile[sp4 + 2][cc]) = *(short4v*)p2;
      *(short4v*)(&tile[sp4 + 3][cc]) = *(short4v*)p3;
    }
  }
  __syncthreads();

  // contiguous 512B-segment stores for both tiles
  const int c8 = (t & 31) * 8;
  const int spb = t >> 5;
#pragma unroll
  for (int k = 0; k < 2; ++k) {
    const ushort_t (*tile)[264] = k ? tB : tA;
    ushort_t* ob = xt + ((size_t)b * HW + (sblk + k) * 32) * 256;
#pragma unroll
    for (int q2 = 0; q2 < 4; ++q2) {
      const int sp = spb + q2 * 8;
      short8 vv = *(const short8*)(&tile[sp][c8]);
      *(short8*)(ob + (size_t)sp * 256 + c8) = vv;
    }
  }
}

// ---------------------------------------------------------------------------
// Sampler (fused com-epilogue). XCD-contiguous work swizzle: 1D grid 800,
// work = (g&7)*100 + (g>>3). 8-px tiles, block 256. Sums 8 split-K slices
// (com conv split-K 8).
// ---------------------------------------------------------------------------
__global__ __launch_bounds__(256) void sample_kernel(
    const ushort_t* __restrict__ xt, const ushort_t* __restrict__ part,
    const float* __restrict__ cbias, ushort_t* __restrict__ colT,
    int Hin, int Win, int stride, int pad, int dil) {
  __shared__ int4  gL[128];
  __shared__ float4 gW[128];
  const int g = blockIdx.x;
  const int work = (g & 7) * 100 + (g >> 3);
  const int b = work / 200;
  const int px0 = (work - b * 200) * 8;
  const int t = threadIdx.x;
  const int HWin = Hin * Win;

  if (t < 128) {  // geometry: pair pid = t -> (px_l = t&7, tap i = t>>3)
    const int px_l = t & 7, i = t >> 3;
    const int p = px0 + px_l;
    const int n = b * 1600 + p;
    const int ph = p / 40, pw = p - (p / 40) * 40;
    float dy = cbias[2 * i], dx = cbias[2 * i + 1], mzr = cbias[32 + i];
#pragma unroll
    for (int kz = 0; kz < 8; ++kz) {
      const ushort_t* pp = part + (size_t)kz * PART_STRIDE + n;
      dy  += bu(pp[(size_t)(2 * i) * 6400]);
      dx  += bu(pp[(size_t)(2 * i + 1) * 6400]);
      mzr += bu(pp[(size_t)(32 + i) * 6400]);
    }
    float mz = 1.f / (1.f + expf(-mzr));
    float py = (float)(ph * stride - pad + (i >> 2) * dil) + dy;
    float px = (float)(pw * stride - pad + (i & 3) * dil) + dx;
    float y0f = floorf(py), x0f = floorf(px);
    float ly = py - y0f, lx = px - x0f;
    int y0 = (int)y0f, x0 = (int)x0f;
    int y1 = y0 + 1, x1 = x0 + 1;
    float hy = 1.f - ly, hx = 1.f - lx;
    float w00 = hy * hx * mz, w01 = hy * lx * mz;
    float w10 = ly * hx * mz, w11 = ly * lx * mz;
    if (y0 < 0 || y0 >= Hin) { w00 = 0.f; w01 = 0.f; }
    if (y1 < 0 || y1 >= Hin) { w10 = 0.f; w11 = 0.f; }
    if (x0 < 0 || x0 >= Win) { w00 = 0.f; w10 = 0.f; }
    if (x1 < 0 || x1 >= Win) { w01 = 0.f; w11 = 0.f; }
    int cy0 = min(max(y0, 0), Hin - 1), cy1 = min(max(y1, 0), Hin - 1);
    int cx0 = min(max(x0, 0), Win - 1), cx1 = min(max(x1, 0), Win - 1);
    gL[t] = make_int4((cy0 * Win + cx0) * 256, (cy0 * Win + cx1) * 256,
                      (cy1 * Win + cx0) * 256, (cy1 * Win + cx1) * 256);
    gW[t] = make_float4(w00, w01, w10, w11);
  }
  __syncthreads();

  const ushort_t* xtb = xt + (size_t)b * HWin * 256;
  const int wv = t >> 6, l = t & 63;
  const int half = l >> 5;
  const int cin8 = (l & 31) * 8;

#pragma unroll 2
  for (int it = 0; it < 16; ++it) {
    const int pr = it * 8 + wv * 2 + half;
    const int4 G = gL[pr];
    const float4 W = gW[pr];
    short8 c00 = *(const short8*)(xtb + G.x + cin8);
    short8 c01 = *(const short8*)(xtb + G.y + cin8);
    short8 c10 = *(const short8*)(xtb + G.z + cin8);
    short8 c11 = *(const short8*)(xtb + G.w + cin8);
    short8 rr;
#pragma unroll
    for (int j = 0; j < 8; ++j) {
      float v = W.x * bu((ushort_t)c00[j]) + W.y * bu((ushort_t)c01[j]) +
                W.z * bu((ushort_t)c10[j]) + W.w * bu((ushort_t)c11[j]);
      rr[j] = (short)fb(v);
    }
    const int px_l = pr & 7, i = pr >> 3;
    *(short8*)(colT + ((size_t)(b * 1600 + px0 + px_l) * 4096 + i * 256 + cin8)) = rr;
  }
}

// ---------------------------------------------------------------------------
// Deform GEMM (K=4096, colT B-matrix), split-K 4, bf16 partials.
// grid 400. XCD-aware decode: id=(g&7)*50+(g>>3) -> mt=id&1, kz=(id>>1)&3,
// nt=id>>3, so the mt-pair sharing one B-tile is always on one XCD (L2 hit),
// and the 4 kz of one nt mostly share that XCD too.
// ---------------------------------------------------------------------------
__global__ __launch_bounds__(256) void gemm_deform(const ushort_t* __restrict__ A,
                                                   const ushort_t* __restrict__ B,
                                                   ushort_t* __restrict__ part) {
  __shared__ ushort_t sA[128 * 32];
  __shared__ ushort_t sB[128 * 32];
  const int g = blockIdx.x;
  const int id = (g & 7) * 50 + (g >> 3);
  const int mt = id & 1, kz = (id >> 1) & 3, nt = id >> 3;
  const int t = threadIdx.x;
  const int wv = t >> 6, l = t & 63;
  const int wm = wv >> 1, wn = wv & 1;

  f4v acc[4][4];
#pragma unroll
  for (int a = 0; a < 4; ++a)
#pragma unroll
    for (int bb = 0; bb < 4; ++bb) acc[a][bb] = (f4v)(0.f);

  const int ra = t >> 2;
  const int q  = ((t & 3) - (ra >> 1)) & 3;
  const size_t aoff = (size_t)(mt * 128 + ra) * 4096 + q * 8;
  const size_t boff = (size_t)(nt * 128 + ra) * 4096 + q * 8;
  ushort_t* lA = sA + t * 8;
  ushort_t* lB = sB + t * 8;

  int k0 = kz * 1024;
  const int lm = l & 15;
  const int koff = (((l >> 4) + (lm >> 1)) & 3) * 8;

  for (int step = 0; step < 32; ++step, k0 += 32) {
    __syncthreads();
    GLD16(A + aoff + k0, lA);
    GLD16(A + aoff + (size_t)64 * 4096 + k0, lA + 2048);
    GLD16(B + boff + k0, lB);
    GLD16(B + boff + (size_t)64 * 4096 + k0, lB + 2048);
    __syncthreads();
    short8 af[4], bfr[4];
#pragma unroll
    for (int fm = 0; fm < 4; ++fm)
      af[fm] = *(const short8*)(sA + (wm * 64 + fm * 16 + lm) * 32 + koff);
#pragma unroll
    for (int fn = 0; fn < 4; ++fn)
      bfr[fn] = *(const short8*)(sB + (wn * 64 + fn * 16 + lm) * 32 + koff);
#pragma unroll
    for (int fm = 0; fm < 4; ++fm)
#pragma unroll
      for (int fn = 0; fn < 4; ++fn)
        acc[fm][fn] = __builtin_amdgcn_mfma_f32_16x16x32_bf16(af[fm], bfr[fn],
                                                              acc[fm][fn], 0, 0, 0);
  }

  const int row_l = (l >> 4) * 4;
  ushort_t* pb = part + (size_t)kz * PART_STRIDE;
#pragma unroll
  for (int fm = 0; fm < 4; ++fm) {
#pragma unroll
    for (int fn = 0; fn < 4; ++fn) {
      const int n = nt * 128 + wn * 64 + fn * 16 + lm;
#pragma unroll
      for (int r = 0; r < 4; ++r) {
        const int m = mt * 128 + wm * 64 + fm * 16 + row_l + r;
        pb[(size_t)m * 6400 + n] = fb(acc[fm][fn][r]);
      }
    }
  }
}

// ---------------------------------------------------------------------------
// 3x3 conv GEMM (com/res) staging B DIRECTLY from NHWC ft40 (no im2col).
// ---------------------------------------------------------------------------
template <int MTILE, int KZ>
__global__ __launch_bounds__(256) void gemm_conv3(const ushort_t* __restrict__ A,
                                                  const ushort_t* __restrict__ ft,
                                                  const ushort_t* __restrict__ zp,
                                                  ushort_t* __restrict__ part,
                                                  int ksteps) {
  constexpr int FN = (MTILE == 128) ? 4 : 2;
  __shared__ ushort_t sA[MTILE * 32];
  __shared__ ushort_t sB[128 * 32];
  const int g = blockIdx.x;
  const int kz = g % KZ;
  const int r = g / KZ;
  const int mt = (MTILE == 128) ? (r & 1) : 0;
  const int nt = (MTILE == 128) ? (r >> 1) : r;
  const int t = threadIdx.x;
  const int wv = t >> 6, l = t & 63;
  const int wm = (MTILE == 128) ? (wv >> 1) : 0;
  const int wn = (MTILE == 128) ? (wv & 1) : wv;

  f4v acc[4][FN];
#pragma unroll
  for (int a = 0; a < 4; ++a)
#pragma unroll
    for (int bb = 0; bb < FN; ++bb) acc[a][bb] = (f4v)(0.f);

  const int ra = t >> 2;
  const int q  = ((t & 3) - (ra >> 1)) & 3;
  const int qc = q * 8;
  const size_t aoff = (size_t)(mt * MTILE + ra) * 2304 + qc;
  const int n0 = nt * 128 + ra;
  const int n1 = n0 + 64;
  const int b0 = n0 / 1600, p0 = n0 - b0 * 1600;
  const int b1 = n1 / 1600, p1 = n1 - b1 * 1600;
  const int ph0 = p0 / 40, pw0 = p0 - (p0 / 40) * 40;
  const int ph1 = p1 / 40, pw1 = p1 - (p1 / 40) * 40;
  const ushort_t* fp0 = ft + (size_t)n0 * 256 + qc;
  const ushort_t* fp1 = ft + (size_t)n1 * 256 + qc;
  ushort_t* lA = sA + t * 8;
  ushort_t* lB = sB + t * 8;

  int k0 = kz * ksteps * 32;
  const int lm = l & 15;
  const int koff = (((l >> 4) + (lm >> 1)) & 3) * 8;

  for (int step = 0; step < ksteps; ++step, k0 += 32) {
    const int tap = k0 >> 8, c0 = k0 & 255;
    const int ky = tap / 3;
    const int dy = ky - 1, dx = (tap - ky * 3) - 1;
    const int off = (dy * 40 + dx) * 256 + c0;
    const bool ok0 = ((unsigned)(ph0 + dy) < 40u) & ((unsigned)(pw0 + dx) < 40u);
    const bool ok1 = ((unsigned)(ph1 + dy) < 40u) & ((unsigned)(pw1 + dx) < 40u);
    const ushort_t* s0 = ok0 ? (fp0 + off) : zp;
    const ushort_t* s1 = ok1 ? (fp1 + off) : zp;
    __syncthreads();
    GLD16(A + aoff + k0, lA);
    if (MTILE == 128) GLD16(A + aoff + (size_t)64 * 2304 + k0, lA + 2048);
    GLD16(s0, lB);
    GLD16(s1, lB + 2048);
    __syncthreads();
    short8 af[4], bfr[FN];
#pragma unroll
    for (int fm = 0; fm < 4; ++fm)
      af[fm] = *(const short8*)(sA + (wm * 64 + fm * 16 + lm) * 32 + koff);
#pragma unroll
    for (int fn = 0; fn < FN; ++fn)
      bfr[fn] = *(const short8*)(sB + (wn * (16 * FN) + fn * 16 + lm) * 32 + koff);
#pragma unroll
    for (int fm = 0; fm < 4; ++fm)
#pragma unroll
      for (int fn = 0; fn < FN; ++fn)
        acc[fm][fn] = __builtin_amdgcn_mfma_f32_16x16x32_bf16(af[fm], bfr[fn],
                                                              acc[fm][fn], 0, 0, 0);
  }

  const int row_l = (l >> 4) * 4;
  ushort_t* pb = part + (size_t)kz * PART_STRIDE;
#pragma unroll
  for (int fm = 0; fm < 4; ++fm) {
#pragma unroll
    for (int fn = 0; fn < FN; ++fn) {
      const int n = nt * 128 + wn * (16 * FN) + fn * 16 + lm;
#pragma unroll
      for (int r = 0; r < 4; ++r) {
        const int m = mt * MTILE + wm * 64 + fm * 16 + row_l + r;
        pb[(size_t)m * 6400 + n] = fb(acc[fm][fn][r]);
      }
    }
  }
}

// ---------------------------------------------------------------------------
// Fused GEMM epilogue (NKZ split-K slices):
// dst_f32[NCHW] = (relu? max(sum+bias,0):sum+bias)+src, and (if ft)
// ft40[NHWC] = bf16(dst) via LDS transpose.
// grid (25, 8, 4): p-tile 64, co-tile 32, batch. block 256.
// ---------------------------------------------------------------------------
template <int NKZ>
__global__ __launch_bounds__(256) void epi_fused(const ushort_t* __restrict__ part,
                                                 const float* __restrict__ bias,
                                                 const float* __restrict__ src,
                                                 float* __restrict__ dst,
                                                 ushort_t* __restrict__ ft, int relu) {
  __shared__ __align__(16) ushort_t tile[32][72];  // [co_l][p_l]
  const int t = threadIdx.x;
  const int p0 = blockIdx.x * 64, c0 = blockIdx.y * 32, b = blockIdx.z;
  const int co_l = t >> 3, pg = t & 7;
  const int co = c0 + co_l;
  const size_t n = (size_t)b * 1600 + p0 + pg * 8;

  float a[8] = {0.f, 0.f, 0.f, 0.f, 0.f, 0.f, 0.f, 0.f};
#pragma unroll
  for (int kz = 0; kz < NKZ; ++kz) {
    short8 pp = *(const short8*)(part + (size_t)kz * PART_STRIDE + (size_t)co * 6400 + n);
#pragma unroll
    for (int j = 0; j < 8; ++j) a[j] += bu((ushort_t)pp[j]);
  }
  const float bv = bias[co];
  const size_t fo = ((size_t)b * 256 + co) * 1600 + p0 + pg * 8;
  float4 s0 = *(const float4*)(src + fo);
  float4 s1 = *(const float4*)(src + fo + 4);
  const float sv[8] = {s0.x, s0.y, s0.z, s0.w, s1.x, s1.y, s1.z, s1.w};
  float o[8];
#pragma unroll
  for (int j = 0; j < 8; ++j) {
    float v = a[j] + bv;
    if (relu) v = fmaxf(v, 0.f);
    o[j] = v + sv[j];
  }
  float4 o0 = {o[0], o[1], o[2], o[3]};
  float4 o1 = {o[4], o[5], o[6], o[7]};
  *(float4*)(dst + fo) = o0;
  *(float4*)(dst + fo + 4) = o1;

  if (ft) {
    short8 rr;
#pragma unroll
    for (int j = 0; j < 8; ++j) rr[j] = (short)fb(o[j]);
    *(short8*)(&tile[co_l][pg * 8]) = rr;
    __syncthreads();
    const int p_l = t >> 2, cb = (t & 3) * 8;
    short8 v;
#pragma unroll
    for (int j = 0; j < 8; ++j) v[j] = (short)tile[cb + j][p_l];
    *(short8*)(ft + ((size_t)(b * 1600 + p0 + p_l)) * 256 + c0 + cb) = v;
  }
}

// ---------------------------------------------------------------------------
extern "C" void kernel_launch(void* const* d_in, const int* in_sizes, int n_in,
                              void* d_out, int out_size, void* d_ws, size_t ws_size,
                              hipStream_t stream) {
  (void)in_sizes; (void)n_in; (void)out_size; (void)ws_size;
  const float* f0     = (const float*)d_in[0];
  const float* f1     = (const float*)d_in[1];
  const float* f2     = (const float*)d_in[2];
  const float* com_w0 = (const float*)d_in[3];
  const float* com_b0 = (const float*)d_in[4];
  const float* com_w1 = (const float*)d_in[5];
  const float* com_b1 = (const float*)d_in[6];
  const float* dcn_w0 = (const float*)d_in[7];
  const float* dcn_b0 = (const float*)d_in[8];
  const float* dcn_w1 = (const float*)d_in[9];
  const float* dcn_b1 = (const float*)d_in[10];
  const float* res_w  = (const float*)d_in[11];
  const float* res_b  = (const float*)d_in[12];
  float* out = (float*)d_out;
  float* ws  = (float*)d_ws;

  // ws layout (float offsets); ~40.3M floats ~= 161 MB
  float*    fbuf  = ws + 0;          // 1,638,400 f32
  ushort_t* A0    = (ushort_t*)(ws + 1700000);   // 1,048,576 u16
  ushort_t* A1    = (ushort_t*)(ws + 2230000);   // 1,048,576 u16
  ushort_t* Acom0 = (ushort_t*)(ws + 2760000);   //   147,456 u16 (64x2304)
  ushort_t* Acom1 = (ushort_t*)(ws + 2840000);   //   147,456 u16
  ushort_t* Ares  = (ushort_t*)(ws + 2920000);   //   589,824 u16 (256x2304)
  ushort_t* ft40  = (ushort_t*)(ws + 3220000);   // 1,638,400 u16
  ushort_t* f1t   = (ushort_t*)(ws + 4050000);   // 6,553,600 u16
  ushort_t* f0t   = (ushort_t*)(ws + 7330000);   // 26,214,400 u16
  ushort_t* colT  = (ushort_t*)(ws + 20440000);  // 26,214,400 u16
  ushort_t* part  = (ushort_t*)(ws + 33550000);  // 13,107,200 u16 (8 bf16 slices)
  ushort_t* zp    = (ushort_t*)(ws + 40110000);  //       256 u16 zero page

  // 2 prep launches: weights+zp, then all three NHWC conversions (v3 tiles)
  prep_all<<<3969, 256, 0, stream>>>(com_w0, com_w1, res_w, dcn_w0, dcn_w1,
                                     Acom0, Acom1, Ares, A0, A1, zp);
  nhwc_all<<<dim3(525, 1, 4), 256, 0, stream>>>(f2, f1, f0, ft40, f1t, f0t);

  const float* fsrc = f2;
  for (int s = 0; s < 4; ++s) {
    int l = s & 1;
    // com conv as GEMM (M=48 pad 64, K=2304, split-K 8 -> 400 blocks)
    gemm_conv3<64, 8><<<400, 256, 0, stream>>>(l ? Acom1 : Acom0, ft40, zp, part, 9);
    // sampler fuses com epilogue (bias + partial-sum + sigmoid)
    if (l == 0) {
      sample_kernel<<<800, 256, 0, stream>>>(f1t, part, com_b0, colT, 80, 80, 2, 1, 1);
    } else {
      sample_kernel<<<800, 256, 0, stream>>>(f0t, part, com_b1, colT, 160, 160, 4, 3, 3);
    }
    // deformable conv GEMM (K=4096, split-K 4, XCD-paired decode)
    gemm_deform<<<400, 256, 0, stream>>>(l ? A1 : A0, colT, part);
    // fused epilogue writes fbuf (f32 NCHW) AND ft40 (bf16 NHWC) for next stage
    epi_fused<4><<<dim3(25, 8, 4), 256, 0, stream>>>(part, l ? dcn_b1 : dcn_b0, fsrc,
                                                     fbuf, ft40, 1);
    fsrc = fbuf;
  }
  // res conv as GEMM (M=256, K=2304, split-K 8); ft40 already written by epi_fused
  gemm_conv3<128, 8><<<800, 256, 0, stream>>>(Ares, ft40, zp, part, 9);
  epi_fused<8><<<dim3(25, 8, 4), 256, 0, stream>>>(part, res_b, f2, out, nullptr, 0);
}

// Round 5
// 517.375 us; speedup vs baseline: 1.0975x; 1.0151x over previous
//
#include <hip/hip_runtime.h>

#define HW40 1600
typedef unsigned short ushort_t;
typedef __attribute__((ext_vector_type(8))) short short8;
typedef __attribute__((ext_vector_type(4))) short short4v;
typedef __attribute__((ext_vector_type(4))) float f4v;

__device__ __forceinline__ float bu(ushort_t u) {
  union { unsigned i; float f; } x; x.i = ((unsigned)u) << 16; return x.f;
}
__device__ __forceinline__ ushort_t fb(float f) {
  union { float f; unsigned i; } x; x.f = f;
  unsigned r = x.i + 0x7FFFu + ((x.i >> 16) & 1u);
  return (ushort_t)(r >> 16);
}

#define GLD16(g, l)                                                            \
  __builtin_amdgcn_global_load_lds(                                            \
      (const __attribute__((address_space(1))) void*)(g),                      \
      (__attribute__((address_space(3))) void*)(l), 16, 0, 0)

#define PART_STRIDE 1638400  // one split-K slice: 256 x 6400

// ---------------------------------------------------------------------------
// Merged prep: zero page + 3x convert_w9 + convert_dcnw in ONE launch.
// ---------------------------------------------------------------------------
__global__ __launch_bounds__(256) void prep_all(
    const float* __restrict__ com_w0, const float* __restrict__ com_w1,
    const float* __restrict__ res_w, const float* __restrict__ dcn_w0,
    const float* __restrict__ dcn_w1, ushort_t* __restrict__ Acom0,
    ushort_t* __restrict__ Acom1, ushort_t* __restrict__ Ares,
    ushort_t* __restrict__ A0, ushort_t* __restrict__ A1,
    ushort_t* __restrict__ zp) {
  __shared__ float s[4096];
  const int g = blockIdx.x;
  const int t = threadIdx.x;
  if (g < 3456) {
    // 3x3 conv weights [co][cin][3][3] fp32 -> A[co][tap*256+cin] bf16
    const float* src; ushort_t* dst; int Cout_src; int base;
    if (g < 576)       { src = com_w0; dst = Acom0; Cout_src = 48;  base = g; }
    else if (g < 1152) { src = com_w1; dst = Acom1; Cout_src = 48;  base = g - 576; }
    else               { src = res_w;  dst = Ares;  Cout_src = 256; base = g - 1152; }
    const int idx = base * 256 + t;
    const int co = idx / 2304;
    const int k  = idx - co * 2304;
    const int cin = k & 255, tap = k >> 8;
    dst[idx] = (co < Cout_src) ? fb(src[(size_t)co * 2304 + cin * 9 + tap]) : (ushort_t)0;
  } else if (g < 3968) {
    // dcn weights [co][cin][16] fp32 -> A_bf16 [co][k = i*256 + cin]
    const int lg = g - 3456;
    const int co = lg & 255;
    const float* w = (lg < 256) ? dcn_w0 : dcn_w1;
    ushort_t* A = (lg < 256) ? A0 : A1;
    const float4* wp = (const float4*)(w + (size_t)co * 4096);
#pragma unroll
    for (int q = 0; q < 4; ++q) ((float4*)s)[t + q * 256] = wp[t + q * 256];
    __syncthreads();
    const int i = t >> 4, cb = (t & 15) * 16;
    ushort_t tmp[16];
#pragma unroll
    for (int j = 0; j < 16; ++j) tmp[j] = fb(s[(cb + j) * 16 + i]);
    ushort_t* op = A + (size_t)co * 4096 + t * 16;
    ((uint4*)op)[0] = ((uint4*)tmp)[0];
    ((uint4*)op)[1] = ((uint4*)tmp)[1];
  } else {
    zp[t] = 0;  // zero page for OOB conv taps
  }
}

// ---------------------------------------------------------------------------
// NCHW fp32 -> NHWC bf16 (v4): contiguous-read tiles.
// SPT=128 (f0/f1): per load instr a wave covers 2 channel rows x 512B
// contiguous; SPT=64 (f2): 4 rows x 256B. Lane map delivers a 4ch x 4sp
// register block per lane (no shuffles): lane l reads sp (l&(LPC-1))*4 of
// channel cb+(l/LPC)*4+j, j=0..3. LDS [SPT][264], one barrier, 512B stores.
// ---------------------------------------------------------------------------
template <int SPT>
__device__ __forceinline__ void nhwc_body(const float* __restrict__ x,
                                          ushort_t* __restrict__ xt,
                                          int HW, int s0, int b,
                                          ushort_t (*tile)[264]) {
  const int t = threadIdx.x;
  const int l = t & 63, wv = t >> 6;
  constexpr int LPC = SPT / 4;       // lanes per channel-row
  constexpr int CPW = (64 / LPC) * 4;  // channels per wave per it
  constexpr int NIT = 256 / (4 * CPW);
  const int spl = (l & (LPC - 1)) * 4;
  const int cgrp = (l / LPC) * 4;
  const float* xb = x + (size_t)b * 256 * HW + s0 + spl;
#pragma unroll
  for (int it = 0; it < NIT; ++it) {
    const int cb = (it * 4 + wv) * CPW + cgrp;
    const float4 v0 = *(const float4*)(xb + (size_t)(cb + 0) * HW);
    const float4 v1 = *(const float4*)(xb + (size_t)(cb + 1) * HW);
    const float4 v2 = *(const float4*)(xb + (size_t)(cb + 2) * HW);
    const float4 v3 = *(const float4*)(xb + (size_t)(cb + 3) * HW);
    ushort_t p0[4] = {fb(v0.x), fb(v1.x), fb(v2.x), fb(v3.x)};
    ushort_t p1[4] = {fb(v0.y), fb(v1.y), fb(v2.y), fb(v3.y)};
    ushort_t p2[4] = {fb(v0.z), fb(v1.z), fb(v2.z), fb(v3.z)};
    ushort_t p3[4] = {fb(v0.w), fb(v1.w), fb(v2.w), fb(v3.w)};
    *(short4v*)(&tile[spl + 0][cb]) = *(short4v*)p0;
    *(short4v*)(&tile[spl + 1][cb]) = *(short4v*)p1;
    *(short4v*)(&tile[spl + 2][cb]) = *(short4v*)p2;
    *(short4v*)(&tile[spl + 3][cb]) = *(short4v*)p3;
  }
  __syncthreads();
  const int c8 = (t & 31) * 8;
  const int spb = t >> 5;
  ushort_t* ob = xt + ((size_t)b * HW + s0) * 256;
#pragma unroll
  for (int q = 0; q < SPT / 8; ++q) {
    const int sp = spb + q * 8;
    *(short8*)(ob + (size_t)sp * 256 + c8) = *(const short8*)(&tile[sp][c8]);
  }
}

// grid x: [0,800) f0 (b=gx/200, tile=gx%200) | [800,1000) f1 | [1000,1100) f2
__global__ __launch_bounds__(256) void nhwc_all(const float* __restrict__ f2,
                                                const float* __restrict__ f1,
                                                const float* __restrict__ f0,
                                                ushort_t* __restrict__ ft40,
                                                ushort_t* __restrict__ f1t,
                                                ushort_t* __restrict__ f0t) {
  __shared__ __align__(16) ushort_t tile[128][264];
  const int gx = blockIdx.x;
  if (gx < 800) {
    nhwc_body<128>(f0, f0t, 25600, (gx % 200) * 128, gx / 200, tile);
  } else if (gx < 1000) {
    const int g1 = gx - 800;
    nhwc_body<128>(f1, f1t, 6400, (g1 % 50) * 128, g1 / 50, tile);
  } else {
    const int g2 = gx - 1000;
    nhwc_body<64>(f2, ft40, 1600, (g2 % 25) * 64, g2 / 25, tile);
  }
}

// ---------------------------------------------------------------------------
// Sampler (fused com-epilogue). XCD-contiguous work swizzle: 1D grid 800,
// work = (g&7)*100 + (g>>3). 8-px tiles, block 256. Sums 8 split-K slices.
// ---------------------------------------------------------------------------
__global__ __launch_bounds__(256) void sample_kernel(
    const ushort_t* __restrict__ xt, const ushort_t* __restrict__ part,
    const float* __restrict__ cbias, ushort_t* __restrict__ colT,
    int Hin, int Win, int stride, int pad, int dil) {
  __shared__ int4  gL[128];
  __shared__ float4 gW[128];
  const int g = blockIdx.x;
  const int work = (g & 7) * 100 + (g >> 3);
  const int b = work / 200;
  const int px0 = (work - b * 200) * 8;
  const int t = threadIdx.x;
  const int HWin = Hin * Win;

  if (t < 128) {  // geometry: pair pid = t -> (px_l = t&7, tap i = t>>3)
    const int px_l = t & 7, i = t >> 3;
    const int p = px0 + px_l;
    const int n = b * 1600 + p;
    const int ph = p / 40, pw = p - (p / 40) * 40;
    float dy = cbias[2 * i], dx = cbias[2 * i + 1], mzr = cbias[32 + i];
#pragma unroll
    for (int kz = 0; kz < 8; ++kz) {
      const ushort_t* pp = part + (size_t)kz * PART_STRIDE + n;
      dy  += bu(pp[(size_t)(2 * i) * 6400]);
      dx  += bu(pp[(size_t)(2 * i + 1) * 6400]);
      mzr += bu(pp[(size_t)(32 + i) * 6400]);
    }
    float mz = 1.f / (1.f + expf(-mzr));
    float py = (float)(ph * stride - pad + (i >> 2) * dil) + dy;
    float px = (float)(pw * stride - pad + (i & 3) * dil) + dx;
    float y0f = floorf(py), x0f = floorf(px);
    float ly = py - y0f, lx = px - x0f;
    int y0 = (int)y0f, x0 = (int)x0f;
    int y1 = y0 + 1, x1 = x0 + 1;
    float hy = 1.f - ly, hx = 1.f - lx;
    float w00 = hy * hx * mz, w01 = hy * lx * mz;
    float w10 = ly * hx * mz, w11 = ly * lx * mz;
    if (y0 < 0 || y0 >= Hin) { w00 = 0.f; w01 = 0.f; }
    if (y1 < 0 || y1 >= Hin) { w10 = 0.f; w11 = 0.f; }
    if (x0 < 0 || x0 >= Win) { w00 = 0.f; w10 = 0.f; }
    if (x1 < 0 || x1 >= Win) { w01 = 0.f; w11 = 0.f; }
    int cy0 = min(max(y0, 0), Hin - 1), cy1 = min(max(y1, 0), Hin - 1);
    int cx0 = min(max(x0, 0), Win - 1), cx1 = min(max(x1, 0), Win - 1);
    gL[t] = make_int4((cy0 * Win + cx0) * 256, (cy0 * Win + cx1) * 256,
                      (cy1 * Win + cx0) * 256, (cy1 * Win + cx1) * 256);
    gW[t] = make_float4(w00, w01, w10, w11);
  }
  __syncthreads();

  const ushort_t* xtb = xt + (size_t)b * HWin * 256;
  const int wv = t >> 6, l = t & 63;
  const int half = l >> 5;
  const int cin8 = (l & 31) * 8;

#pragma unroll 2
  for (int it = 0; it < 16; ++it) {
    const int pr = it * 8 + wv * 2 + half;
    const int4 G = gL[pr];
    const float4 W = gW[pr];
    short8 c00 = *(const short8*)(xtb + G.x + cin8);
    short8 c01 = *(const short8*)(xtb + G.y + cin8);
    short8 c10 = *(const short8*)(xtb + G.z + cin8);
    short8 c11 = *(const short8*)(xtb + G.w + cin8);
    short8 rr;
#pragma unroll
    for (int j = 0; j < 8; ++j) {
      float v = W.x * bu((ushort_t)c00[j]) + W.y * bu((ushort_t)c01[j]) +
                W.z * bu((ushort_t)c10[j]) + W.w * bu((ushort_t)c11[j]);
      rr[j] = (short)fb(v);
    }
    const int px_l = pr & 7, i = pr >> 3;
    *(short8*)(colT + ((size_t)(b * 1600 + px0 + px_l) * 4096 + i * 256 + cin8)) = rr;
  }
}

// ---------------------------------------------------------------------------
// Deform GEMM (K=4096, colT B-matrix), split-K 4, bf16 partials.
// grid 400. XCD-aware decode: id=(g&7)*50+(g>>3) -> mt=id&1, kz=(id>>1)&3,
// nt=id>>3, so the mt-pair sharing one B-tile is always on one XCD (L2 hit),
// and the 4 kz of one nt mostly share that XCD too.
// ---------------------------------------------------------------------------
__global__ __launch_bounds__(256) void gemm_deform(const ushort_t* __restrict__ A,
                                                   const ushort_t* __restrict__ B,
                                                   ushort_t* __restrict__ part) {
  __shared__ ushort_t sA[128 * 32];
  __shared__ ushort_t sB[128 * 32];
  const int g = blockIdx.x;
  const int id = (g & 7) * 50 + (g >> 3);
  const int mt = id & 1, kz = (id >> 1) & 3, nt = id >> 3;
  const int t = threadIdx.x;
  const int wv = t >> 6, l = t & 63;
  const int wm = wv >> 1, wn = wv & 1;

  f4v acc[4][4];
#pragma unroll
  for (int a = 0; a < 4; ++a)
#pragma unroll
    for (int bb = 0; bb < 4; ++bb) acc[a][bb] = (f4v)(0.f);

  const int ra = t >> 2;
  const int q  = ((t & 3) - (ra >> 1)) & 3;
  const size_t aoff = (size_t)(mt * 128 + ra) * 4096 + q * 8;
  const size_t boff = (size_t)(nt * 128 + ra) * 4096 + q * 8;
  ushort_t* lA = sA + t * 8;
  ushort_t* lB = sB + t * 8;

  int k0 = kz * 1024;
  const int lm = l & 15;
  const int koff = (((l >> 4) + (lm >> 1)) & 3) * 8;

  for (int step = 0; step < 32; ++step, k0 += 32) {
    __syncthreads();
    GLD16(A + aoff + k0, lA);
    GLD16(A + aoff + (size_t)64 * 4096 + k0, lA + 2048);
    GLD16(B + boff + k0, lB);
    GLD16(B + boff + (size_t)64 * 4096 + k0, lB + 2048);
    __syncthreads();
    short8 af[4], bfr[4];
#pragma unroll
    for (int fm = 0; fm < 4; ++fm)
      af[fm] = *(const short8*)(sA + (wm * 64 + fm * 16 + lm) * 32 + koff);
#pragma unroll
    for (int fn = 0; fn < 4; ++fn)
      bfr[fn] = *(const short8*)(sB + (wn * 64 + fn * 16 + lm) * 32 + koff);
#pragma unroll
    for (int fm = 0; fm < 4; ++fm)
#pragma unroll
      for (int fn = 0; fn < 4; ++fn)
        acc[fm][fn] = __builtin_amdgcn_mfma_f32_16x16x32_bf16(af[fm], bfr[fn],
                                                              acc[fm][fn], 0, 0, 0);
  }

  const int row_l = (l >> 4) * 4;
  ushort_t* pb = part + (size_t)kz * PART_STRIDE;
#pragma unroll
  for (int fm = 0; fm < 4; ++fm) {
#pragma unroll
    for (int fn = 0; fn < 4; ++fn) {
      const int n = nt * 128 + wn * 64 + fn * 16 + lm;
#pragma unroll
      for (int r = 0; r < 4; ++r) {
        const int m = mt * 128 + wm * 64 + fm * 16 + row_l + r;
        pb[(size_t)m * 6400 + n] = fb(acc[fm][fn][r]);
      }
    }
  }
}

// ---------------------------------------------------------------------------
// 3x3 conv GEMM (com/res) staging B DIRECTLY from NHWC ft40 (no im2col).
// XCD-contiguous decode: id=(g&7)*(grid/8)+(g>>3); kz=id&7, r=id>>3 -> all
// 8 kz (and mt-pair) of one B-panel land on one XCD's L2.
// ---------------------------------------------------------------------------
template <int MTILE, int KZ>
__global__ __launch_bounds__(256) void gemm_conv3(const ushort_t* __restrict__ A,
                                                  const ushort_t* __restrict__ ft,
                                                  const ushort_t* __restrict__ zp,
                                                  ushort_t* __restrict__ part,
                                                  int ksteps) {
  constexpr int FN = (MTILE == 128) ? 4 : 2;
  __shared__ ushort_t sA[MTILE * 32];
  __shared__ ushort_t sB[128 * 32];
  const int g = blockIdx.x;
  const int id = (g & 7) * (gridDim.x >> 3) + (g >> 3);
  const int kz = id % KZ;
  const int r = id / KZ;
  const int mt = (MTILE == 128) ? (r & 1) : 0;
  const int nt = (MTILE == 128) ? (r >> 1) : r;
  const int t = threadIdx.x;
  const int wv = t >> 6, l = t & 63;
  const int wm = (MTILE == 128) ? (wv >> 1) : 0;
  const int wn = (MTILE == 128) ? (wv & 1) : wv;

  f4v acc[4][FN];
#pragma unroll
  for (int a = 0; a < 4; ++a)
#pragma unroll
    for (int bb = 0; bb < FN; ++bb) acc[a][bb] = (f4v)(0.f);

  const int ra = t >> 2;
  const int q  = ((t & 3) - (ra >> 1)) & 3;
  const int qc = q * 8;
  const size_t aoff = (size_t)(mt * MTILE + ra) * 2304 + qc;
  const int n0 = nt * 128 + ra;
  const int n1 = n0 + 64;
  const int b0 = n0 / 1600, p0 = n0 - b0 * 1600;
  const int b1 = n1 / 1600, p1 = n1 - b1 * 1600;
  const int ph0 = p0 / 40, pw0 = p0 - (p0 / 40) * 40;
  const int ph1 = p1 / 40, pw1 = p1 - (p1 / 40) * 40;
  const ushort_t* fp0 = ft + (size_t)n0 * 256 + qc;
  const ushort_t* fp1 = ft + (size_t)n1 * 256 + qc;
  ushort_t* lA = sA + t * 8;
  ushort_t* lB = sB + t * 8;

  int k0 = kz * ksteps * 32;
  const int lm = l & 15;
  const int koff = (((l >> 4) + (lm >> 1)) & 3) * 8;

  for (int step = 0; step < ksteps; ++step, k0 += 32) {
    const int tap = k0 >> 8, c0 = k0 & 255;
    const int ky = tap / 3;
    const int dy = ky - 1, dx = (tap - ky * 3) - 1;
    const int off = (dy * 40 + dx) * 256 + c0;
    const bool ok0 = ((unsigned)(ph0 + dy) < 40u) & ((unsigned)(pw0 + dx) < 40u);
    const bool ok1 = ((unsigned)(ph1 + dy) < 40u) & ((unsigned)(pw1 + dx) < 40u);
    const ushort_t* s0 = ok0 ? (fp0 + off) : zp;
    const ushort_t* s1 = ok1 ? (fp1 + off) : zp;
    __syncthreads();
    GLD16(A + aoff + k0, lA);
    if (MTILE == 128) GLD16(A + aoff + (size_t)64 * 2304 + k0, lA + 2048);
    GLD16(s0, lB);
    GLD16(s1, lB + 2048);
    __syncthreads();
    short8 af[4], bfr[FN];
#pragma unroll
    for (int fm = 0; fm < 4; ++fm)
      af[fm] = *(const short8*)(sA + (wm * 64 + fm * 16 + lm) * 32 + koff);
#pragma unroll
    for (int fn = 0; fn < FN; ++fn)
      bfr[fn] = *(const short8*)(sB + (wn * (16 * FN) + fn * 16 + lm) * 32 + koff);
#pragma unroll
    for (int fm = 0; fm < 4; ++fm)
#pragma unroll
      for (int fn = 0; fn < FN; ++fn)
        acc[fm][fn] = __builtin_amdgcn_mfma_f32_16x16x32_bf16(af[fm], bfr[fn],
                                                              acc[fm][fn], 0, 0, 0);
  }

  const int row_l = (l >> 4) * 4;
  ushort_t* pb = part + (size_t)kz * PART_STRIDE;
#pragma unroll
  for (int fm = 0; fm < 4; ++fm) {
#pragma unroll
    for (int fn = 0; fn < FN; ++fn) {
      const int n = nt * 128 + wn * (16 * FN) + fn * 16 + lm;
#pragma unroll
      for (int r = 0; r < 4; ++r) {
        const int m = mt * MTILE + wm * 64 + fm * 16 + row_l + r;
        pb[(size_t)m * 6400 + n] = fb(acc[fm][fn][r]);
      }
    }
  }
}

// ---------------------------------------------------------------------------
// Fused GEMM epilogue (NKZ split-K slices):
// dst_f32[NCHW] = (relu? max(sum+bias,0):sum+bias)+src, and (if ft)
// ft40[NHWC] = bf16(dst) via LDS transpose.
// grid (25, 8, 4): p-tile 64, co-tile 32, batch. block 256.
// ---------------------------------------------------------------------------
template <int NKZ>
__global__ __launch_bounds__(256) void epi_fused(const ushort_t* __restrict__ part,
                                                 const float* __restrict__ bias,
                                                 const float* __restrict__ src,
                                                 float* __restrict__ dst,
                                                 ushort_t* __restrict__ ft, int relu) {
  __shared__ __align__(16) ushort_t tile[32][72];  // [co_l][p_l]
  const int t = threadIdx.x;
  const int p0 = blockIdx.x * 64, c0 = blockIdx.y * 32, b = blockIdx.z;
  const int co_l = t >> 3, pg = t & 7;
  const int co = c0 + co_l;
  const size_t n = (size_t)b * 1600 + p0 + pg * 8;

  float a[8] = {0.f, 0.f, 0.f, 0.f, 0.f, 0.f, 0.f, 0.f};
#pragma unroll
  for (int kz = 0; kz < NKZ; ++kz) {
    short8 pp = *(const short8*)(part + (size_t)kz * PART_STRIDE + (size_t)co * 6400 + n);
#pragma unroll
    for (int j = 0; j < 8; ++j) a[j] += bu((ushort_t)pp[j]);
  }
  const float bv = bias[co];
  const size_t fo = ((size_t)b * 256 + co) * 1600 + p0 + pg * 8;
  float4 s0 = *(const float4*)(src + fo);
  float4 s1 = *(const float4*)(src + fo + 4);
  const float sv[8] = {s0.x, s0.y, s0.z, s0.w, s1.x, s1.y, s1.z, s1.w};
  float o[8];
#pragma unroll
  for (int j = 0; j < 8; ++j) {
    float v = a[j] + bv;
    if (relu) v = fmaxf(v, 0.f);
    o[j] = v + sv[j];
  }
  float4 o0 = {o[0], o[1], o[2], o[3]};
  float4 o1 = {o[4], o[5], o[6], o[7]};
  *(float4*)(dst + fo) = o0;
  *(float4*)(dst + fo + 4) = o1;

  if (ft) {
    short8 rr;
#pragma unroll
    for (int j = 0; j < 8; ++j) rr[j] = (short)fb(o[j]);
    *(short8*)(&tile[co_l][pg * 8]) = rr;
    __syncthreads();
    const int p_l = t >> 2, cb = (t & 3) * 8;
    short8 v;
#pragma unroll
    for (int j = 0; j < 8; ++j) v[j] = (short)tile[cb + j][p_l];
    *(short8*)(ft + ((size_t)(b * 1600 + p0 + p_l)) * 256 + c0 + cb) = v;
  }
}

// ---------------------------------------------------------------------------
extern "C" void kernel_launch(void* const* d_in, const int* in_sizes, int n_in,
                              void* d_out, int out_size, void* d_ws, size_t ws_size,
                              hipStream_t stream) {
  (void)in_sizes; (void)n_in; (void)out_size; (void)ws_size;
  const float* f0     = (const float*)d_in[0];
  const float* f1     = (const float*)d_in[1];
  const float* f2     = (const float*)d_in[2];
  const float* com_w0 = (const float*)d_in[3];
  const float* com_b0 = (const float*)d_in[4];
  const float* com_w1 = (const float*)d_in[5];
  const float* com_b1 = (const float*)d_in[6];
  const float* dcn_w0 = (const float*)d_in[7];
  const float* dcn_b0 = (const float*)d_in[8];
  const float* dcn_w1 = (const float*)d_in[9];
  const float* dcn_b1 = (const float*)d_in[10];
  const float* res_w  = (const float*)d_in[11];
  const float* res_b  = (const float*)d_in[12];
  float* out = (float*)d_out;
  float* ws  = (float*)d_ws;

  // ws layout (float offsets); ~40.3M floats ~= 161 MB
  float*    fbuf  = ws + 0;          // 1,638,400 f32
  ushort_t* A0    = (ushort_t*)(ws + 1700000);   // 1,048,576 u16
  ushort_t* A1    = (ushort_t*)(ws + 2230000);   // 1,048,576 u16
  ushort_t* Acom0 = (ushort_t*)(ws + 2760000);   //   147,456 u16 (64x2304)
  ushort_t* Acom1 = (ushort_t*)(ws + 2840000);   //   147,456 u16
  ushort_t* Ares  = (ushort_t*)(ws + 2920000);   //   589,824 u16 (256x2304)
  ushort_t* ft40  = (ushort_t*)(ws + 3220000);   // 1,638,400 u16
  ushort_t* f1t   = (ushort_t*)(ws + 4050000);   // 6,553,600 u16
  ushort_t* f0t   = (ushort_t*)(ws + 7330000);   // 26,214,400 u16
  ushort_t* colT  = (ushort_t*)(ws + 20440000);  // 26,214,400 u16
  ushort_t* part  = (ushort_t*)(ws + 33550000);  // 13,107,200 u16 (8 bf16 slices)
  ushort_t* zp    = (ushort_t*)(ws + 40110000);  //       256 u16 zero page

  // 2 prep launches: weights+zp, then all three NHWC conversions (v4 tiles)
  prep_all<<<3969, 256, 0, stream>>>(com_w0, com_w1, res_w, dcn_w0, dcn_w1,
                                     Acom0, Acom1, Ares, A0, A1, zp);
  nhwc_all<<<dim3(1100, 1, 1), 256, 0, stream>>>(f2, f1, f0, ft40, f1t, f0t);

  const float* fsrc = f2;
  for (int s = 0; s < 4; ++s) {
    int l = s & 1;
    // com conv as GEMM (M=48 pad 64, K=2304, split-K 8 -> 400 blocks)
    gemm_conv3<64, 8><<<400, 256, 0, stream>>>(l ? Acom1 : Acom0, ft40, zp, part, 9);
    // sampler fuses com epilogue (bias + partial-sum + sigmoid)
    if (l == 0) {
      sample_kernel<<<800, 256, 0, stream>>>(f1t, part, com_b0, colT, 80, 80, 2, 1, 1);
    } else {
      sample_kernel<<<800, 256, 0, stream>>>(f0t, part, com_b1, colT, 160, 160, 4, 3, 3);
    }
    // deformable conv GEMM (K=4096, split-K 4, XCD-paired decode)
    gemm_deform<<<400, 256, 0, stream>>>(l ? A1 : A0, colT, part);
    // fused epilogue writes fbuf (f32 NCHW) AND ft40 (bf16 NHWC) for next stage
    epi_fused<4><<<dim3(25, 8, 4), 256, 0, stream>>>(part, l ? dcn_b1 : dcn_b0, fsrc,
                                                     fbuf, ft40, 1);
    fsrc = fbuf;
  }
  // res conv as GEMM (M=256, K=2304, split-K 8); ft40 already written by epi_fused
  gemm_conv3<128, 8><<<800, 256, 0, stream>>>(Ares, ft40, zp, part, 9);
  epi_fused<8><<<dim3(25, 8, 4), 256, 0, stream>>>(part, res_b, f2, out, nullptr, 0);
}